// Round 5
// baseline (173.193 us; speedup 1.0000x reference)
//
#include <hip/hip_runtime.h>
#include <hip/hip_bf16.h>
#include <math.h>

#define NB 8
#define NN 512
#define NC 256
#define HID 32

typedef __attribute__((ext_vector_type(8))) short short8;
typedef __attribute__((ext_vector_type(4))) float float4v;
typedef unsigned short ushort_t;

__device__ __forceinline__ ushort_t f2bf(float x) {
    unsigned u = __float_as_uint(x);
    return (ushort_t)((u + 0x7fffu + ((u >> 16) & 1u)) >> 16);
}
__device__ __forceinline__ float bf2f(ushort_t h) {
    return __uint_as_float(((unsigned)h) << 16);
}

// ---------------------------------------------------------------------------
// Kernel 1: front_gemms, 512 blocks (2/CU).
//   blocks [0,256):   xab = x @ [wa|wb] (+eb1); zero dsum/gmax/done.
//   blocks [256,512): T0  = (x @ gw0)^T bf16, UNSCALED (d-scaling in L0).
// Register-prefetch + LDS double-buffer: ONE barrier per K-step.
// ---------------------------------------------------------------------------
__global__ __launch_bounds__(256) void front_gemms(
    const float* __restrict__ x, const float* __restrict__ ew1,
    const float* __restrict__ eb1, const float* __restrict__ gw0,
    float* __restrict__ xab, ushort_t* __restrict__ T0,
    float* __restrict__ dsum, unsigned* __restrict__ gmax, int* __restrict__ done)
{
    __shared__ __align__(16) union {
        struct { float sX[2][32][17]; float sW[2][32][68]; } a;
        struct { float sH[2][32][17]; float sW[2][32][132]; ushort_t sTh[128][24]; } b;
    } u;
    int t = threadIdx.x;

    if (blockIdx.x < 256) {
        // ---- role A: xab = x @ [wa|wb]
        if (blockIdx.x < 32) dsum[blockIdx.x * 256 + t] = 0.f;
        if (blockIdx.x == 32) {
            gmax[t] = 0u; gmax[t + 256] = 0u;
            if (t < NB) done[t] = 0;
        }
        int r0 = blockIdx.x * 16;
        int tx = t & 15, ty = t >> 4;
        int xk = (t & 15) * 2, xr = t >> 4;
        int c4 = (t & 15) * 4;
        int whalf = c4 >> 5, wcc = c4 & 31;
        float acc[4] = {0.f, 0.f, 0.f, 0.f};

        float2 rx = *(const float2*)(x + (size_t)(r0 + xr) * NC + xk);
        float4 rw0 = *(const float4*)(ew1 + (size_t)(whalf * NC + xr) * HID + wcc);
        float4 rw1 = *(const float4*)(ew1 + (size_t)(whalf * NC + xr + 16) * HID + wcc);

        for (int k0 = 0; k0 < NC; k0 += 32) {
            int cur = (k0 >> 5) & 1;
            u.a.sX[cur][xk][xr] = rx.x; u.a.sX[cur][xk + 1][xr] = rx.y;
            *(float4*)&u.a.sW[cur][xr][c4] = rw0;
            *(float4*)&u.a.sW[cur][xr + 16][c4] = rw1;
            if (k0 + 32 < NC) {
                rx  = *(const float2*)(x + (size_t)(r0 + xr) * NC + k0 + 32 + xk);
                rw0 = *(const float4*)(ew1 + (size_t)(whalf * NC + k0 + 32 + xr) * HID + wcc);
                rw1 = *(const float4*)(ew1 + (size_t)(whalf * NC + k0 + 32 + xr + 16) * HID + wcc);
            }
            __syncthreads();
#pragma unroll
            for (int k = 0; k < 32; ++k) {
                float a = u.a.sX[cur][k][ty];
                float4 w = *(const float4*)&u.a.sW[cur][k][tx * 4];
                acc[0] = fmaf(a, w.x, acc[0]); acc[1] = fmaf(a, w.y, acc[1]);
                acc[2] = fmaf(a, w.z, acc[2]); acc[3] = fmaf(a, w.w, acc[3]);
            }
        }
        int oc4 = tx * 4;
        float4 o; o.x = acc[0]; o.y = acc[1]; o.z = acc[2]; o.w = acc[3];
        if (oc4 >= 32) {
            o.x += eb1[oc4 - 32]; o.y += eb1[oc4 - 31];
            o.z += eb1[oc4 - 30]; o.w += eb1[oc4 - 29];
        }
        *(float4*)&xab[(size_t)(r0 + ty) * 64 + oc4] = o;
    } else {
        // ---- role B: T0 = (x @ gw0)^T, unscaled bf16
        int r0 = (blockIdx.x - 256) * 16;
        int tx = t & 31, ty = t >> 5;
        int xk = (t & 15) * 2, xr = t >> 4;
        int c4w = (t & 31) * 4;
        int whalf = c4w >> 6, wcc = c4w & 63;
        int wk = t >> 5;
        float acc0[4] = {0.f, 0.f, 0.f, 0.f};
        float acc1[4] = {0.f, 0.f, 0.f, 0.f};

        float2 rx = *(const float2*)(x + (size_t)(r0 + xr) * NC + xk);
        float4 rw[4];
#pragma unroll
        for (int rr = 0; rr < 4; ++rr)
            rw[rr] = *(const float4*)(gw0 + (size_t)(whalf * NC + wk + rr * 8) * 64 + wcc);

        for (int k0 = 0; k0 < NC; k0 += 32) {
            int cur = (k0 >> 5) & 1;
            u.b.sH[cur][xk][xr] = rx.x; u.b.sH[cur][xk + 1][xr] = rx.y;
#pragma unroll
            for (int rr = 0; rr < 4; ++rr)
                *(float4*)&u.b.sW[cur][wk + rr * 8][c4w] = rw[rr];
            if (k0 + 32 < NC) {
                rx = *(const float2*)(x + (size_t)(r0 + xr) * NC + k0 + 32 + xk);
#pragma unroll
                for (int rr = 0; rr < 4; ++rr)
                    rw[rr] = *(const float4*)(gw0 + (size_t)(whalf * NC + k0 + 32 + wk + rr * 8) * 64 + wcc);
            }
            __syncthreads();
#pragma unroll
            for (int k = 0; k < 32; ++k) {
                float a0 = u.b.sH[cur][k][ty * 2];
                float a1 = u.b.sH[cur][k][ty * 2 + 1];
                float4 w = *(const float4*)&u.b.sW[cur][k][tx * 4];
                acc0[0] = fmaf(a0, w.x, acc0[0]); acc0[1] = fmaf(a0, w.y, acc0[1]);
                acc0[2] = fmaf(a0, w.z, acc0[2]); acc0[3] = fmaf(a0, w.w, acc0[3]);
                acc1[0] = fmaf(a1, w.x, acc1[0]); acc1[1] = fmaf(a1, w.y, acc1[1]);
                acc1[2] = fmaf(a1, w.z, acc1[2]); acc1[3] = fmaf(a1, w.w, acc1[3]);
            }
        }
        __syncthreads();
        int c4 = tx * 4;
#pragma unroll
        for (int r = 0; r < 2; ++r) {
            int rl = ty * 2 + r;
            float* ap = (r == 0) ? acc0 : acc1;
#pragma unroll
            for (int n = 0; n < 4; ++n)
                u.b.sTh[c4 + n][rl] = f2bf(ap[n]);
        }
        __syncthreads();
        {
            int c = t & 127, half = t >> 7;
            int bb = r0 >> 9, ibase = r0 & (NN - 1);
            ushort_t* dst = T0 + ((size_t)(bb * 128 + c)) * NN + ibase + half * 8;
            *(short8*)dst = *(const short8*)&u.b.sTh[c][half * 8];
        }
    }
}

// ---------------------------------------------------------------------------
// Kernel 2: edge scores -> AP bf16 + AP col sums + A->bf16 + A col sums.
// (verbatim from r4: register-hoisted j-row, b128 sI reads, rW in VGPRs)
// ---------------------------------------------------------------------------
__global__ __launch_bounds__(256) void edge_scores(
    const float* __restrict__ xab, const float* __restrict__ ew2,
    const float* __restrict__ eb2, const float* __restrict__ mask,
    const float* __restrict__ A, ushort_t* __restrict__ Ah,
    ushort_t* __restrict__ APh, float* __restrict__ dsum)
{
    __shared__ __align__(16) float sI[32][68], sJ[32][68];
    __shared__ float sV[32][33];
    int b = blockIdx.z;
    int p = blockIdx.x;
    int X = 0;
    while ((X + 1) * 16 - ((X + 1) * X) / 2 <= p) ++X;
    int Y = X + (p - (X * 16 - (X * (X - 1)) / 2));
    int i0 = X * 32, j0 = Y * 32;
    int t = threadIdx.x;
    int tj = t & 31;

    float4 rW[8];
#pragma unroll
    for (int k4 = 0; k4 < 8; ++k4) rW[k4] = *(const float4*)(ew2 + k4 * 4);
    float eb2v = eb2[0];

    {
        int c4 = (t & 15) * 4;
#pragma unroll
        for (int rr = 0; rr < 2; ++rr) {
            int r = (t >> 4) + rr * 16;
            float4 vi = *(const float4*)(xab + ((size_t)(b * NN + i0 + r)) * 64 + c4);
            float4 vj = *(const float4*)(xab + ((size_t)(b * NN + j0 + r)) * 64 + c4);
            *(float4*)&sI[r][c4] = vi;
            *(float4*)&sJ[r][c4] = vj;
        }
    }
    __syncthreads();

    float rJlo[32], rJhi[32];
#pragma unroll
    for (int k4 = 0; k4 < 8; ++k4) {
        float4 a4 = *(const float4*)&sJ[tj][k4 * 4];
        float4 b4 = *(const float4*)&sJ[tj][32 + k4 * 4];
        rJlo[k4 * 4 + 0] = a4.x; rJlo[k4 * 4 + 1] = a4.y;
        rJlo[k4 * 4 + 2] = a4.z; rJlo[k4 * 4 + 3] = a4.w;
        rJhi[k4 * 4 + 0] = b4.x; rJhi[k4 * 4 + 1] = b4.y;
        rJhi[k4 * 4 + 2] = b4.z; rJhi[k4 * 4 + 3] = b4.w;
    }
    float mj = mask[b * NN + j0 + tj];

#pragma unroll
    for (int pz = 0; pz < 4; ++pz) {
        int ti = (t >> 5) + pz * 8;
        float sij = 0.f, sji = 0.f;
#pragma unroll
        for (int k4 = 0; k4 < 8; ++k4) {
            float4 ia = *(const float4*)&sI[ti][k4 * 4];
            float4 ib = *(const float4*)&sI[ti][32 + k4 * 4];
            float4 wv = rW[k4];
            sij = fmaf(fmaxf(ia.x + rJhi[k4 * 4 + 0], 0.f), wv.x, sij);
            sji = fmaf(fmaxf(rJlo[k4 * 4 + 0] + ib.x, 0.f), wv.x, sji);
            sij = fmaf(fmaxf(ia.y + rJhi[k4 * 4 + 1], 0.f), wv.y, sij);
            sji = fmaf(fmaxf(rJlo[k4 * 4 + 1] + ib.y, 0.f), wv.y, sji);
            sij = fmaf(fmaxf(ia.z + rJhi[k4 * 4 + 2], 0.f), wv.z, sij);
            sji = fmaf(fmaxf(rJlo[k4 * 4 + 2] + ib.z, 0.f), wv.z, sji);
            sij = fmaf(fmaxf(ia.w + rJhi[k4 * 4 + 3], 0.f), wv.w, sij);
            sji = fmaf(fmaxf(rJlo[k4 * 4 + 3] + ib.w, 0.f), wv.w, sji);
        }
        int i = i0 + ti, j = j0 + tj;
        bool ok = (i != j) && (mask[b * NN + i] > 0.f) && (mj > 0.f);
        sV[ti][tj] = ok ? expf(0.5f * (sij + sji) + eb2v) : 0.f;
    }
    __syncthreads();
#pragma unroll
    for (int pz = 0; pz < 4; ++pz) {
        int r = (t >> 5) + pz * 8, c = t & 31;
        size_t o1 = ((size_t)(b * NN + i0 + r)) * NN + j0 + c;
        size_t o2 = ((size_t)(b * NN + j0 + r)) * NN + i0 + c;
        APh[o1] = f2bf(sV[r][c]);
        APh[o2] = f2bf(sV[c][r]);
    }
    if (t < 32) {
        float s = 0.f;
#pragma unroll
        for (int r = 0; r < 32; ++r) s += sV[r][t];
        atomicAdd(&dsum[(NB * NN) + b * NN + j0 + t], s);
    } else if (t < 64 && X != Y) {
        int c = t - 32;
        float s = 0.f;
#pragma unroll
        for (int j = 0; j < 32; ++j) s += sV[c][j];
        atomicAdd(&dsum[(NB * NN) + b * NN + i0 + c], s);
    }
    if (p < 128) {
        const float* Ar = A + ((size_t)b * NN + 4 * p) * NN;
        ushort_t* Hr = Ah + ((size_t)b * NN + 4 * p) * NN;
        float s0 = 0.f, s1 = 0.f;
#pragma unroll
        for (int rr = 0; rr < 4; ++rr) {
            float a0 = Ar[(size_t)rr * NN + t];
            float a1 = Ar[(size_t)rr * NN + t + 256];
            Hr[(size_t)rr * NN + t] = f2bf(a0);
            Hr[(size_t)rr * NN + t + 256] = f2bf(a1);
            s0 += a0; s1 += a1;
        }
        atomicAdd(&dsum[b * NN + t], s0);
        atomicAdd(&dsum[b * NN + t + 256], s1);
    }
}

// ---------------------------------------------------------------------------
// Kernel 3/4/5: fused layer, grid (32, 2, NB) = 512 blocks.
// Phase A: DIRECT-LOAD barrier-free MFMA K-loop — every lane's fragment is a
//   contiguous 16B run of global Ah/APh/P, loaded straight into operand regs.
//   No LDS staging, no per-K-step barriers; compiler pipelines freely.
//   scaleP=1 (L0): in-register d_j scaling from the sDj LDS table (bit-exact
//   vs staged variant). Epilogue pv/dsum prefetched before the loop.
// LDS drops 57KB -> ~21KB.
// ---------------------------------------------------------------------------
__global__ __launch_bounds__(256) void fused_layer(
    const ushort_t* __restrict__ Ah, const ushort_t* __restrict__ APh,
    const ushort_t* __restrict__ Pa, const ushort_t* __restrict__ Pb,
    ushort_t* __restrict__ Qa, ushort_t* __restrict__ Qb,
    const float* __restrict__ dsum, const float* __restrict__ gb,
    const float* __restrict__ mask, const float* __restrict__ gwN,
    unsigned* __restrict__ gmax, int* __restrict__ done,
    const float* __restrict__ fcw, const float* __restrict__ fcb,
    float* __restrict__ out, int dualP, int mode, int scaleP)
{
    __shared__ ushort_t sWT[128][40];
    __shared__ float sRed[2][32][17];
    __shared__ float sH16[16][36];
    __shared__ float sD[2][16];
    __shared__ __align__(16) float sDj[2][NN];
    __shared__ int lastFlag;

    int t = threadIdx.x;
    int b = blockIdx.z, ch = blockIdx.y, i0 = blockIdx.x * 16;
    int lane = t & 63, w = t >> 6;
    int quad = lane >> 4, m16 = lane & 15;
    int lap = w >> 1, cg = w & 1;

    // d_j table for layer-0 in-register scale (both laplacians, all 512 cols)
    if (scaleP) {
#pragma unroll
        for (int s = 0; s < 4; ++s) {
            int idx = t + s * 256;
            int lp = idx >> 9, j = idx & (NN - 1);
            sDj[lp][j] = rsqrtf(dsum[lp * (NB * NN) + b * NN + j] + 1.0f + 1e-5f);
        }
        __syncthreads();
    }

    // per-lane global fragment bases (contiguous 16B runs)
    const ushort_t* Abase = (lap ? APh : Ah)
        + ((size_t)(b * NN + i0 + m16)) * NN + quad * 8;
    int prow = b * 128 + lap * 64 + ch * 32 + cg * 16 + m16;
    const ushort_t* P1base = Pa + (size_t)prow * NN + quad * 8;
    const ushort_t* P2base = Pb + (size_t)prow * NN + quad * 8;

    // prefetch epilogue operands (hidden under the K-loop)
    int gi = b * NN + i0 + m16;
    float dspre = dsum[lap * (NB * NN) + gi];
    int cbase = cg * 16 + quad * 4;
    size_t pvbase = ((size_t)(b * 128 + lap * 64 + ch * 32 + cbase)) * NN + i0 + m16;
    ushort_t pvA[4], pvB[4];
#pragma unroll
    for (int r = 0; r < 4; ++r) {
        pvA[r] = Pa[pvbase + (size_t)r * NN];
        pvB[r] = dualP ? Pb[pvbase + (size_t)r * NN] : (ushort_t)0;
    }

    float4v acc = {0.f, 0.f, 0.f, 0.f};

#pragma unroll
    for (int k0 = 0; k0 < NN; k0 += 64) {
#pragma unroll
        for (int kh = 0; kh < 2; ++kh) {
            int ko = k0 + kh * 32;
            short8 av = *(const short8*)(Abase + ko);
            short8 p1 = *(const short8*)(P1base + ko);
            if (scaleP) {
                float4v dja = *(const float4v*)&sDj[lap][ko + quad * 8];
                float4v djb = *(const float4v*)&sDj[lap][ko + quad * 8 + 4];
                short8 w0;
#pragma unroll
                for (int e = 0; e < 4; ++e) {
                    w0[e]     = (short)f2bf(bf2f((ushort_t)p1[e])     * dja[e]);
                    w0[e + 4] = (short)f2bf(bf2f((ushort_t)p1[e + 4]) * djb[e]);
                }
                p1 = w0;
            }
            acc = __builtin_amdgcn_mfma_f32_16x16x32_bf16(p1, av, acc, 0, 0, 0);
            if (dualP) {
                short8 p2 = *(const short8*)(P2base + ko);
                acc = __builtin_amdgcn_mfma_f32_16x16x32_bf16(p2, av, acc, 0, 0, 0);
            }
        }
    }

    // epilogue -> sRed, capture d into sD
    float d = rsqrtf(dspre + 1.0f + 1e-5f);
    if (cg == 0 && quad == 0) sD[lap][m16] = d;
#pragma unroll
    for (int r = 0; r < 4; ++r) {
        int c32 = cbase + r;
        float pv = bf2f(pvA[r]);
        if (dualP) pv += bf2f(pvB[r]);
        if (scaleP) pv *= d;
        sRed[lap][c32][m16] = d * (acc[r] + pv);
    }
    __syncthreads();
    // combine laps + bias + mask + relu -> sH16
#pragma unroll
    for (int s = 0; s < 2; ++s) {
        int idx = t + s * 256;
        int c32 = idx & 31, i = idx >> 5;
        float mv = mask[b * NN + i0 + i];
        float v = (sRed[0][c32][i] + sRed[1][c32][i] + gb[ch * 32 + c32]) * mv;
        sH16[i][c32] = fmaxf(v, 0.f);
    }
    __syncthreads();

    if (mode == 0) {
        // ---- phase B: partial pre for next layer via MFMA, K=32
#pragma unroll
        for (int kk = 0; kk < 8; ++kk) {
            int chunk = t + kk * 256;            // 0..2047
            int c = chunk & 127;
            int k = (chunk >> 7) * 2;            // even k
            int base = (c < 64) ? (ch * 32) : (64 + ch * 32);
            int gc = c & 63;
            float f0 = gwN[(size_t)(base + k) * 64 + gc];
            float f1 = gwN[(size_t)(base + k + 1) * 64 + gc];
            unsigned pk = (unsigned)f2bf(f0) | ((unsigned)f2bf(f1) << 16);
            *(unsigned*)&sWT[c][k] = pk;
        }
        __syncthreads();
        float4 h0 = *(const float4*)&sH16[m16][quad * 8];
        float4 h1 = *(const float4*)&sH16[m16][quad * 8 + 4];
        short8 bfv;
        bfv[0] = f2bf(h0.x); bfv[1] = f2bf(h0.y); bfv[2] = f2bf(h0.z); bfv[3] = f2bf(h0.w);
        bfv[4] = f2bf(h1.x); bfv[5] = f2bf(h1.y); bfv[6] = f2bf(h1.z); bfv[7] = f2bf(h1.w);
        ushort_t* Q = ch ? Qb : Qa;
#pragma unroll
        for (int s2 = 0; s2 < 2; ++s2) {
            int ctile = w * 2 + s2;              // 0..7
            short8 af = *(const short8*)&sWT[ctile * 16 + m16][quad * 8];
            float4v dacc = {0.f, 0.f, 0.f, 0.f};
            dacc = __builtin_amdgcn_mfma_f32_16x16x32_bf16(af, bfv, dacc, 0, 0, 0);
            float dsc = sD[(ctile >= 4) ? 1 : 0][m16];
#pragma unroll
            for (int r = 0; r < 4; ++r) {
                int c = ctile * 16 + quad * 4 + r;
                Q[((size_t)(b * 128 + c)) * NN + i0 + m16] = f2bf(dsc * dacc[r]);
            }
        }
    } else {
        // ---- phase C: max-pool + FC
        if (t < 32) {
            float mx = 0.f;
#pragma unroll
            for (int r = 0; r < 16; ++r) mx = fmaxf(mx, sH16[r][t]);
            atomicMax(&gmax[b * 64 + ch * 32 + t], __float_as_uint(mx));
        }
        __syncthreads();
        if (t == 0) {
            __threadfence();
            int old = atomicAdd(&done[b], 1);
            lastFlag = (old == 63);
        }
        __syncthreads();
        if (lastFlag) {
            if (t < 64) {
                unsigned ub = __hip_atomic_load(&gmax[b * 64 + t],
                                                __ATOMIC_RELAXED,
                                                __HIP_MEMORY_SCOPE_AGENT);
                ((float*)sRed)[t] = __uint_as_float(ub);
            }
            __syncthreads();
            if (t < 2) {
                float a2 = fcb[t];
#pragma unroll
                for (int k = 0; k < 64; ++k)
                    a2 = fmaf(((float*)sRed)[k], fcw[k * 2 + t], a2);
                out[b * 2 + t] = a2;
            }
        }
    }
}

extern "C" void kernel_launch(void* const* d_in, const int* in_sizes, int n_in,
                              void* d_out, int out_size, void* d_ws, size_t ws_size,
                              hipStream_t stream)
{
    const float* x    = (const float*)d_in[0];
    const float* A    = (const float*)d_in[1];
    const float* mask = (const float*)d_in[2];
    const float* ew1  = (const float*)d_in[3];
    const float* eb1  = (const float*)d_in[4];
    const float* ew2  = (const float*)d_in[5];
    const float* eb2  = (const float*)d_in[6];
    const float* gw0  = (const float*)d_in[7];
    const float* gb0  = (const float*)d_in[8];
    const float* gw1  = (const float*)d_in[9];
    const float* gb1  = (const float*)d_in[10];
    const float* gw2  = (const float*)d_in[11];
    const float* gb2  = (const float*)d_in[12];
    const float* fcw  = (const float*)d_in[13];
    const float* fcb  = (const float*)d_in[14];
    float* out = (float*)d_out;
    char* ws = (char*)d_ws;

    const size_t NEL = (size_t)NB * NN * NN;      // 2,097,152
    const size_t PSL = (size_t)NB * 128 * NN;     // 524,288 (one P slice)
    float*    xab  = (float*)ws;                   ws += 262144 * 4;
    ushort_t* APh  = (ushort_t*)ws;                ws += NEL * 2;
    ushort_t* Ahs  = (ushort_t*)ws;                ws += NEL * 2;
    float*    dsum = (float*)ws;                   ws += 8192 * 4;
    ushort_t* PT_A = (ushort_t*)ws;                ws += PSL * 2;  // UNSCALED T0
    ushort_t* PB1a = (ushort_t*)ws;                ws += PSL * 2;
    ushort_t* PB1b = (ushort_t*)ws;                ws += PSL * 2;
    ushort_t* PB2a = (ushort_t*)ws;                ws += PSL * 2;
    ushort_t* PB2b = (ushort_t*)ws;                ws += PSL * 2;
    unsigned* gmax = (unsigned*)ws;                ws += 512 * 4;
    int*      done = (int*)ws;                     ws += 64 * 4;

    // front GEMMs: xab + unscaled T0 in one launch (512 blocks, 2/CU)
    front_gemms<<<512, 256, 0, stream>>>(x, ew1, eb1, gw0, xab, PT_A,
                                         dsum, gmax, done);
    edge_scores<<<dim3(136, 1, NB), 256, 0, stream>>>(xab, ew2, eb2, mask,
                                                      A, Ahs, APh, dsum);

    // layer 0: single-P (unscaled T0, scaleP=1), emits PB1 slices
    fused_layer<<<dim3(32, 2, NB), 256, 0, stream>>>(
        Ahs, APh, PT_A, PT_A, PB1a, PB1b, dsum, gb0, mask, gw1,
        gmax, done, fcw, fcb, out, 0, 0, 1);
    // layer 1: dual-P (PB1), emits PB2 slices
    fused_layer<<<dim3(32, 2, NB), 256, 0, stream>>>(
        Ahs, APh, PB1a, PB1b, PB2a, PB2b, dsum, gb1, mask, gw2,
        gmax, done, fcw, fcb, out, 1, 0, 0);
    // layer 2: dual-P (PB2), final max-pool + FC
    fused_layer<<<dim3(32, 2, NB), 256, 0, stream>>>(
        Ahs, APh, PB2a, PB2b, PB2a, PB2b, dsum, gb2, mask, gw2,
        gmax, done, fcw, fcb, out, 1, 1, 0);
}

// Round 6
// 152.764 us; speedup vs baseline: 1.1337x; 1.1337x over previous
//
#include <hip/hip_runtime.h>
#include <hip/hip_bf16.h>
#include <math.h>

#define NB 8
#define NN 512
#define NC 256
#define HID 32

typedef __attribute__((ext_vector_type(8))) short short8;
typedef __attribute__((ext_vector_type(4))) float float4v;
typedef unsigned short ushort_t;

__device__ __forceinline__ ushort_t f2bf(float x) {
    unsigned u = __float_as_uint(x);
    return (ushort_t)((u + 0x7fffu + ((u >> 16) & 1u)) >> 16);
}
__device__ __forceinline__ float bf2f(ushort_t h) {
    return __uint_as_float(((unsigned)h) << 16);
}

// ---------------------------------------------------------------------------
// Kernel 1: front_gemms, 576 blocks.
//   blocks [0,256):   xab = x @ [wa|wb] (+eb1); zero AP-dsum/gmax/done.
//   blocks [256,512): T0  = (x @ gw0)^T bf16, UNSCALED (d-scaling in L0).
//   blocks [512,576): A -> bf16 (Ah) + A col sums -> dsum (direct, no atomics;
//                     single writer per entry).
// GEMM roles: register-prefetch + LDS double-buffer, ONE barrier per K-step.
// ---------------------------------------------------------------------------
__global__ __launch_bounds__(256) void front_gemms(
    const float* __restrict__ x, const float* __restrict__ ew1,
    const float* __restrict__ eb1, const float* __restrict__ gw0,
    const float* __restrict__ A, ushort_t* __restrict__ Ah,
    float* __restrict__ xab, ushort_t* __restrict__ T0,
    float* __restrict__ dsum, unsigned* __restrict__ gmax, int* __restrict__ done)
{
    __shared__ __align__(16) union {
        struct { float sX[2][32][17]; float sW[2][32][68]; } a;
        struct { float sH[2][32][17]; float sW[2][32][132]; ushort_t sTh[128][24]; } b;
    } u;
    __shared__ float sCol[4][64];
    int t = threadIdx.x;

    if (blockIdx.x < 256) {
        // ---- role A: xab = x @ [wa|wb]
        if (blockIdx.x < 16) dsum[(NB * NN) + blockIdx.x * 256 + t] = 0.f;  // AP half only
        if (blockIdx.x == 16) {
            gmax[t] = 0u; gmax[t + 256] = 0u;
            if (t < NB) done[t] = 0;
        }
        int r0 = blockIdx.x * 16;
        int tx = t & 15, ty = t >> 4;
        int xk = (t & 15) * 2, xr = t >> 4;
        int c4 = (t & 15) * 4;
        int whalf = c4 >> 5, wcc = c4 & 31;
        float acc[4] = {0.f, 0.f, 0.f, 0.f};

        float2 rx = *(const float2*)(x + (size_t)(r0 + xr) * NC + xk);
        float4 rw0 = *(const float4*)(ew1 + (size_t)(whalf * NC + xr) * HID + wcc);
        float4 rw1 = *(const float4*)(ew1 + (size_t)(whalf * NC + xr + 16) * HID + wcc);

        for (int k0 = 0; k0 < NC; k0 += 32) {
            int cur = (k0 >> 5) & 1;
            u.a.sX[cur][xk][xr] = rx.x; u.a.sX[cur][xk + 1][xr] = rx.y;
            *(float4*)&u.a.sW[cur][xr][c4] = rw0;
            *(float4*)&u.a.sW[cur][xr + 16][c4] = rw1;
            if (k0 + 32 < NC) {
                rx  = *(const float2*)(x + (size_t)(r0 + xr) * NC + k0 + 32 + xk);
                rw0 = *(const float4*)(ew1 + (size_t)(whalf * NC + k0 + 32 + xr) * HID + wcc);
                rw1 = *(const float4*)(ew1 + (size_t)(whalf * NC + k0 + 32 + xr + 16) * HID + wcc);
            }
            __syncthreads();
#pragma unroll
            for (int k = 0; k < 32; ++k) {
                float a = u.a.sX[cur][k][ty];
                float4 w = *(const float4*)&u.a.sW[cur][k][tx * 4];
                acc[0] = fmaf(a, w.x, acc[0]); acc[1] = fmaf(a, w.y, acc[1]);
                acc[2] = fmaf(a, w.z, acc[2]); acc[3] = fmaf(a, w.w, acc[3]);
            }
        }
        int oc4 = tx * 4;
        float4 o; o.x = acc[0]; o.y = acc[1]; o.z = acc[2]; o.w = acc[3];
        if (oc4 >= 32) {
            o.x += eb1[oc4 - 32]; o.y += eb1[oc4 - 31];
            o.z += eb1[oc4 - 30]; o.w += eb1[oc4 - 29];
        }
        *(float4*)&xab[(size_t)(r0 + ty) * 64 + oc4] = o;
    } else if (blockIdx.x < 512) {
        // ---- role B: T0 = (x @ gw0)^T, unscaled bf16
        int r0 = (blockIdx.x - 256) * 16;
        int tx = t & 31, ty = t >> 5;
        int xk = (t & 15) * 2, xr = t >> 4;
        int c4w = (t & 31) * 4;
        int whalf = c4w >> 6, wcc = c4w & 63;
        int wk = t >> 5;
        float acc0[4] = {0.f, 0.f, 0.f, 0.f};
        float acc1[4] = {0.f, 0.f, 0.f, 0.f};

        float2 rx = *(const float2*)(x + (size_t)(r0 + xr) * NC + xk);
        float4 rw[4];
#pragma unroll
        for (int rr = 0; rr < 4; ++rr)
            rw[rr] = *(const float4*)(gw0 + (size_t)(whalf * NC + wk + rr * 8) * 64 + wcc);

        for (int k0 = 0; k0 < NC; k0 += 32) {
            int cur = (k0 >> 5) & 1;
            u.b.sH[cur][xk][xr] = rx.x; u.b.sH[cur][xk + 1][xr] = rx.y;
#pragma unroll
            for (int rr = 0; rr < 4; ++rr)
                *(float4*)&u.b.sW[cur][wk + rr * 8][c4w] = rw[rr];
            if (k0 + 32 < NC) {
                rx = *(const float2*)(x + (size_t)(r0 + xr) * NC + k0 + 32 + xk);
#pragma unroll
                for (int rr = 0; rr < 4; ++rr)
                    rw[rr] = *(const float4*)(gw0 + (size_t)(whalf * NC + k0 + 32 + wk + rr * 8) * 64 + wcc);
            }
            __syncthreads();
#pragma unroll
            for (int k = 0; k < 32; ++k) {
                float a0 = u.b.sH[cur][k][ty * 2];
                float a1 = u.b.sH[cur][k][ty * 2 + 1];
                float4 w = *(const float4*)&u.b.sW[cur][k][tx * 4];
                acc0[0] = fmaf(a0, w.x, acc0[0]); acc0[1] = fmaf(a0, w.y, acc0[1]);
                acc0[2] = fmaf(a0, w.z, acc0[2]); acc0[3] = fmaf(a0, w.w, acc0[3]);
                acc1[0] = fmaf(a1, w.x, acc1[0]); acc1[1] = fmaf(a1, w.y, acc1[1]);
                acc1[2] = fmaf(a1, w.z, acc1[2]); acc1[3] = fmaf(a1, w.w, acc1[3]);
            }
        }
        __syncthreads();
        int c4 = tx * 4;
#pragma unroll
        for (int r = 0; r < 2; ++r) {
            int rl = ty * 2 + r;
            float* ap = (r == 0) ? acc0 : acc1;
#pragma unroll
            for (int n = 0; n < 4; ++n)
                u.b.sTh[c4 + n][rl] = f2bf(ap[n]);
        }
        __syncthreads();
        {
            int c = t & 127, half = t >> 7;
            int bb = r0 >> 9, ibase = r0 & (NN - 1);
            ushort_t* dst = T0 + ((size_t)(bb * 128 + c)) * NN + ibase + half * 8;
            *(short8*)dst = *(const short8*)&u.b.sTh[c][half * 8];
        }
    } else {
        // ---- role C: A -> bf16 + direct col sums (single writer per col)
        int c = blockIdx.x - 512;         // 0..63
        int b = c >> 3, q = c & 7;        // batch, column-group of 64
        int col = q * 64 + (t & 63);
        int r0 = t >> 6;                  // 0..3
        const float* Ab = A + (size_t)b * NN * NN;
        ushort_t* Hb = Ah + (size_t)b * NN * NN;
        float s = 0.f;
        for (int it = 0; it < 128; ++it) {
            int row = r0 + 4 * it;
            float a = Ab[(size_t)row * NN + col];
            Hb[(size_t)row * NN + col] = f2bf(a);
            s += a;
        }
        sCol[r0][t & 63] = s;
        __syncthreads();
        if (t < 64)
            dsum[b * NN + q * 64 + t] =
                sCol[0][t] + sCol[1][t] + sCol[2][t] + sCol[3][t];
    }
}

// ---------------------------------------------------------------------------
// Kernel 2: edge scores -> AP bf16 + AP col sums (atomic). A-conversion
// moved to front_gemms role C. Register-hoisted inner loop (r4).
// ---------------------------------------------------------------------------
__global__ __launch_bounds__(256) void edge_scores(
    const float* __restrict__ xab, const float* __restrict__ ew2,
    const float* __restrict__ eb2, const float* __restrict__ mask,
    ushort_t* __restrict__ APh, float* __restrict__ dsum)
{
    __shared__ __align__(16) float sI[32][68], sJ[32][68];
    __shared__ float sV[32][33];
    int b = blockIdx.z;
    int p = blockIdx.x;
    int X = 0;
    while ((X + 1) * 16 - ((X + 1) * X) / 2 <= p) ++X;
    int Y = X + (p - (X * 16 - (X * (X - 1)) / 2));
    int i0 = X * 32, j0 = Y * 32;
    int t = threadIdx.x;
    int tj = t & 31;

    float4 rW[8];
#pragma unroll
    for (int k4 = 0; k4 < 8; ++k4) rW[k4] = *(const float4*)(ew2 + k4 * 4);
    float eb2v = eb2[0];

    {
        int c4 = (t & 15) * 4;
#pragma unroll
        for (int rr = 0; rr < 2; ++rr) {
            int r = (t >> 4) + rr * 16;
            float4 vi = *(const float4*)(xab + ((size_t)(b * NN + i0 + r)) * 64 + c4);
            float4 vj = *(const float4*)(xab + ((size_t)(b * NN + j0 + r)) * 64 + c4);
            *(float4*)&sI[r][c4] = vi;
            *(float4*)&sJ[r][c4] = vj;
        }
    }
    __syncthreads();

    float rJlo[32], rJhi[32];
#pragma unroll
    for (int k4 = 0; k4 < 8; ++k4) {
        float4 a4 = *(const float4*)&sJ[tj][k4 * 4];
        float4 b4 = *(const float4*)&sJ[tj][32 + k4 * 4];
        rJlo[k4 * 4 + 0] = a4.x; rJlo[k4 * 4 + 1] = a4.y;
        rJlo[k4 * 4 + 2] = a4.z; rJlo[k4 * 4 + 3] = a4.w;
        rJhi[k4 * 4 + 0] = b4.x; rJhi[k4 * 4 + 1] = b4.y;
        rJhi[k4 * 4 + 2] = b4.z; rJhi[k4 * 4 + 3] = b4.w;
    }
    float mj = mask[b * NN + j0 + tj];

#pragma unroll
    for (int pz = 0; pz < 4; ++pz) {
        int ti = (t >> 5) + pz * 8;
        float sij = 0.f, sji = 0.f;
#pragma unroll
        for (int k4 = 0; k4 < 8; ++k4) {
            float4 ia = *(const float4*)&sI[ti][k4 * 4];
            float4 ib = *(const float4*)&sI[ti][32 + k4 * 4];
            float4 wv = rW[k4];
            sij = fmaf(fmaxf(ia.x + rJhi[k4 * 4 + 0], 0.f), wv.x, sij);
            sji = fmaf(fmaxf(rJlo[k4 * 4 + 0] + ib.x, 0.f), wv.x, sji);
            sij = fmaf(fmaxf(ia.y + rJhi[k4 * 4 + 1], 0.f), wv.y, sij);
            sji = fmaf(fmaxf(rJlo[k4 * 4 + 1] + ib.y, 0.f), wv.y, sji);
            sij = fmaf(fmaxf(ia.z + rJhi[k4 * 4 + 2], 0.f), wv.z, sij);
            sji = fmaf(fmaxf(rJlo[k4 * 4 + 2] + ib.z, 0.f), wv.z, sji);
            sij = fmaf(fmaxf(ia.w + rJhi[k4 * 4 + 3], 0.f), wv.w, sij);
            sji = fmaf(fmaxf(rJlo[k4 * 4 + 3] + ib.w, 0.f), wv.w, sji);
        }
        int i = i0 + ti, j = j0 + tj;
        bool ok = (i != j) && (mask[b * NN + i] > 0.f) && (mj > 0.f);
        sV[ti][tj] = ok ? expf(0.5f * (sij + sji) + eb2v) : 0.f;
    }
    __syncthreads();
#pragma unroll
    for (int pz = 0; pz < 4; ++pz) {
        int r = (t >> 5) + pz * 8, c = t & 31;
        size_t o1 = ((size_t)(b * NN + i0 + r)) * NN + j0 + c;
        size_t o2 = ((size_t)(b * NN + j0 + r)) * NN + i0 + c;
        APh[o1] = f2bf(sV[r][c]);
        APh[o2] = f2bf(sV[c][r]);
    }
    if (t < 32) {
        float s = 0.f;
#pragma unroll
        for (int r = 0; r < 32; ++r) s += sV[r][t];
        atomicAdd(&dsum[(NB * NN) + b * NN + j0 + t], s);
    } else if (t < 64 && X != Y) {
        int c = t - 32;
        float s = 0.f;
#pragma unroll
        for (int j = 0; j < 32; ++j) s += sV[c][j];
        atomicAdd(&dsum[(NB * NN) + b * NN + i0 + c], s);
    }
}

// ---------------------------------------------------------------------------
// Kernel 3/4/5: fused layer, grid (32, 2, NB) = 512 blocks (2/CU).
// Phase A: reg-prefetch + LDS double-buffer -> ONE barrier per K-step.
// Epilogue pv/dsum loads prefetched BEFORE the K-loop (latency hidden).
// scaleP=1 applies d_j during staging (layer 0, unscaled T0 input).
// (r4 structure verbatim — the direct-load variant of r5 regressed.)
// ---------------------------------------------------------------------------
__global__ __launch_bounds__(256) void fused_layer(
    const ushort_t* __restrict__ Ah, const ushort_t* __restrict__ APh,
    const ushort_t* __restrict__ Pa, const ushort_t* __restrict__ Pb,
    ushort_t* __restrict__ Qa, ushort_t* __restrict__ Qb,
    const float* __restrict__ dsum, const float* __restrict__ gb,
    const float* __restrict__ mask, const float* __restrict__ gwN,
    unsigned* __restrict__ gmax, int* __restrict__ done,
    const float* __restrict__ fcw, const float* __restrict__ fcb,
    float* __restrict__ out, int dualP, int mode, int scaleP)
{
    __shared__ union {
        struct {
            ushort_t sA[2][2][16][72];
            ushort_t sP1[2][64][72];
            ushort_t sP2[2][64][72];
        } a;
        struct { ushort_t sWT[128][40]; } b;    // W^T bf16 for phase B
    } u;
    __shared__ float sRed[2][32][17];
    __shared__ float sH16[16][36];
    __shared__ float sD[2][16];
    __shared__ __align__(16) float sDj[2][NN];
    __shared__ int lastFlag;

    int t = threadIdx.x;
    int b = blockIdx.z, ch = blockIdx.y, i0 = blockIdx.x * 16;
    int lane = t & 63, w = t >> 6;
    int quad = lane >> 4, m16 = lane & 15;
    int lap = w >> 1, cg = w & 1;

    // d_j table for layer-0 staging scale (both laplacians, all 512 cols)
    if (scaleP) {
#pragma unroll
        for (int s = 0; s < 4; ++s) {
            int idx = t + s * 256;
            int lp = idx >> 9, j = idx & (NN - 1);
            sDj[lp][j] = rsqrtf(dsum[lp * (NB * NN) + b * NN + j] + 1.0f + 1e-5f);
        }
    }

    // ---- phase A: dual-lap MFMA GEMM over K=512, dbuf pipelined
    int sa_arr = t >> 7, sa_id = t & 127;
    int sa_r = sa_id >> 3, sa_q = sa_id & 7;
    const ushort_t* sa_src = (sa_arr ? APh : Ah)
        + ((size_t)(b * NN + i0 + sa_r)) * NN + sa_q * 8;
    int pl0 = t >> 3, pq = t & 7;
    size_t poff0 = ((size_t)(b * 128 + ch * 32 + pl0)) * NN + pq * 8;
    size_t poff1 = ((size_t)(b * 128 + 64 + ch * 32 + pl0)) * NN + pq * 8;

    // prefetch epilogue operands (hidden under the K-loop)
    int gi = b * NN + i0 + m16;
    float dspre = dsum[lap * (NB * NN) + gi];
    int cbase = cg * 16 + quad * 4;
    size_t pvbase = ((size_t)(b * 128 + lap * 64 + ch * 32 + cbase)) * NN + i0 + m16;
    ushort_t pvA[4], pvB[4];
#pragma unroll
    for (int r = 0; r < 4; ++r) {
        pvA[r] = Pa[pvbase + (size_t)r * NN];
        pvB[r] = dualP ? Pb[pvbase + (size_t)r * NN] : (ushort_t)0;
    }

    float4v acc = {0.f, 0.f, 0.f, 0.f};

    short8 rA   = *(const short8*)(sa_src);
    short8 rP1a = *(const short8*)(Pa + poff0);
    short8 rP1b = *(const short8*)(Pa + poff1);
    short8 rP2a = rP1a, rP2b = rP1b;
    if (dualP) {
        rP2a = *(const short8*)(Pb + poff0);
        rP2b = *(const short8*)(Pb + poff1);
    }
    __syncthreads();   // sDj visible before first staging read (scaleP)

    for (int k0 = 0; k0 < NN; k0 += 64) {
        int cur = (k0 >> 6) & 1;
        *(short8*)&u.a.sA[cur][sa_arr][sa_r][sa_q * 8] = rA;
        if (scaleP) {
            float4v d0a = *(const float4v*)&sDj[0][k0 + pq * 8];
            float4v d0b = *(const float4v*)&sDj[0][k0 + pq * 8 + 4];
            float4v d1a = *(const float4v*)&sDj[1][k0 + pq * 8];
            float4v d1b = *(const float4v*)&sDj[1][k0 + pq * 8 + 4];
            short8 w0, w1;
#pragma unroll
            for (int e = 0; e < 4; ++e) {
                w0[e]     = (short)f2bf(bf2f((ushort_t)rP1a[e])     * d0a[e]);
                w0[e + 4] = (short)f2bf(bf2f((ushort_t)rP1a[e + 4]) * d0b[e]);
                w1[e]     = (short)f2bf(bf2f((ushort_t)rP1b[e])     * d1a[e]);
                w1[e + 4] = (short)f2bf(bf2f((ushort_t)rP1b[e + 4]) * d1b[e]);
            }
            *(short8*)&u.a.sP1[cur][pl0][pq * 8] = w0;
            *(short8*)&u.a.sP1[cur][32 + pl0][pq * 8] = w1;
        } else {
            *(short8*)&u.a.sP1[cur][pl0][pq * 8] = rP1a;
            *(short8*)&u.a.sP1[cur][32 + pl0][pq * 8] = rP1b;
            if (dualP) {
                *(short8*)&u.a.sP2[cur][pl0][pq * 8] = rP2a;
                *(short8*)&u.a.sP2[cur][32 + pl0][pq * 8] = rP2b;
            }
        }
        if (k0 + 64 < NN) {
            rA   = *(const short8*)(sa_src + k0 + 64);
            rP1a = *(const short8*)(Pa + poff0 + k0 + 64);
            rP1b = *(const short8*)(Pa + poff1 + k0 + 64);
            if (dualP) {
                rP2a = *(const short8*)(Pb + poff0 + k0 + 64);
                rP2b = *(const short8*)(Pb + poff1 + k0 + 64);
            }
        }
        __syncthreads();
#pragma unroll
        for (int kh = 0; kh < 2; ++kh) {
            int ko = kh * 32 + quad * 8;
            short8 av = *(const short8*)&u.a.sA[cur][lap][m16][ko];
            short8 p1 = *(const short8*)&u.a.sP1[cur][w * 16 + m16][ko];
            acc = __builtin_amdgcn_mfma_f32_16x16x32_bf16(p1, av, acc, 0, 0, 0);
            if (dualP) {
                short8 p2 = *(const short8*)&u.a.sP2[cur][w * 16 + m16][ko];
                acc = __builtin_amdgcn_mfma_f32_16x16x32_bf16(p2, av, acc, 0, 0, 0);
            }
        }
    }
    // epilogue -> sRed, capture d into sD
    float d = rsqrtf(dspre + 1.0f + 1e-5f);
    if (cg == 0 && quad == 0) sD[lap][m16] = d;
#pragma unroll
    for (int r = 0; r < 4; ++r) {
        int c32 = cbase + r;
        float pv = bf2f(pvA[r]);
        if (dualP) pv += bf2f(pvB[r]);
        if (scaleP) pv *= d;
        sRed[lap][c32][m16] = d * (acc[r] + pv);
    }
    __syncthreads();
    // combine laps + bias + mask + relu -> sH16
#pragma unroll
    for (int s = 0; s < 2; ++s) {
        int idx = t + s * 256;
        int c32 = idx & 31, i = idx >> 5;
        float mv = mask[b * NN + i0 + i];
        float v = (sRed[0][c32][i] + sRed[1][c32][i] + gb[ch * 32 + c32]) * mv;
        sH16[i][c32] = fmaxf(v, 0.f);
    }
    __syncthreads();

    if (mode == 0) {
        // ---- phase B: partial pre for next layer via MFMA, K=32
#pragma unroll
        for (int kk = 0; kk < 8; ++kk) {
            int chunk = t + kk * 256;            // 0..2047
            int c = chunk & 127;
            int k = (chunk >> 7) * 2;            // even k
            int base = (c < 64) ? (ch * 32) : (64 + ch * 32);
            int gc = c & 63;
            float f0 = gwN[(size_t)(base + k) * 64 + gc];
            float f1 = gwN[(size_t)(base + k + 1) * 64 + gc];
            unsigned pk = (unsigned)f2bf(f0) | ((unsigned)f2bf(f1) << 16);
            *(unsigned*)&u.b.sWT[c][k] = pk;
        }
        __syncthreads();
        float4 h0 = *(const float4*)&sH16[m16][quad * 8];
        float4 h1 = *(const float4*)&sH16[m16][quad * 8 + 4];
        short8 bfv;
        bfv[0] = f2bf(h0.x); bfv[1] = f2bf(h0.y); bfv[2] = f2bf(h0.z); bfv[3] = f2bf(h0.w);
        bfv[4] = f2bf(h1.x); bfv[5] = f2bf(h1.y); bfv[6] = f2bf(h1.z); bfv[7] = f2bf(h1.w);
        ushort_t* Q = ch ? Qb : Qa;
#pragma unroll
        for (int s2 = 0; s2 < 2; ++s2) {
            int ctile = w * 2 + s2;              // 0..7
            short8 af = *(const short8*)&u.b.sWT[ctile * 16 + m16][quad * 8];
            float4v dacc = {0.f, 0.f, 0.f, 0.f};
            dacc = __builtin_amdgcn_mfma_f32_16x16x32_bf16(af, bfv, dacc, 0, 0, 0);
            float dsc = sD[(ctile >= 4) ? 1 : 0][m16];
#pragma unroll
            for (int r = 0; r < 4; ++r) {
                int c = ctile * 16 + quad * 4 + r;
                Q[((size_t)(b * 128 + c)) * NN + i0 + m16] = f2bf(dsc * dacc[r]);
            }
        }
    } else {
        // ---- phase C: max-pool + FC
        if (t < 32) {
            float mx = 0.f;
#pragma unroll
            for (int r = 0; r < 16; ++r) mx = fmaxf(mx, sH16[r][t]);
            atomicMax(&gmax[b * 64 + ch * 32 + t], __float_as_uint(mx));
        }
        __syncthreads();
        if (t == 0) {
            __threadfence();
            int old = atomicAdd(&done[b], 1);
            lastFlag = (old == 63);
        }
        __syncthreads();
        if (lastFlag) {
            if (t < 64) {
                unsigned ub = __hip_atomic_load(&gmax[b * 64 + t],
                                                __ATOMIC_RELAXED,
                                                __HIP_MEMORY_SCOPE_AGENT);
                ((float*)sRed)[t] = __uint_as_float(ub);
            }
            __syncthreads();
            if (t < 2) {
                float a2 = fcb[t];
#pragma unroll
                for (int k = 0; k < 64; ++k)
                    a2 = fmaf(((float*)sRed)[k], fcw[k * 2 + t], a2);
                out[b * 2 + t] = a2;
            }
        }
    }
}

extern "C" void kernel_launch(void* const* d_in, const int* in_sizes, int n_in,
                              void* d_out, int out_size, void* d_ws, size_t ws_size,
                              hipStream_t stream)
{
    const float* x    = (const float*)d_in[0];
    const float* A    = (const float*)d_in[1];
    const float* mask = (const float*)d_in[2];
    const float* ew1  = (const float*)d_in[3];
    const float* eb1  = (const float*)d_in[4];
    const float* ew2  = (const float*)d_in[5];
    const float* eb2  = (const float*)d_in[6];
    const float* gw0  = (const float*)d_in[7];
    const float* gb0  = (const float*)d_in[8];
    const float* gw1  = (const float*)d_in[9];
    const float* gb1  = (const float*)d_in[10];
    const float* gw2  = (const float*)d_in[11];
    const float* gb2  = (const float*)d_in[12];
    const float* fcw  = (const float*)d_in[13];
    const float* fcb  = (const float*)d_in[14];
    float* out = (float*)d_out;
    char* ws = (char*)d_ws;

    const size_t NEL = (size_t)NB * NN * NN;      // 2,097,152
    const size_t PSL = (size_t)NB * 128 * NN;     // 524,288 (one P slice)
    float*    xab  = (float*)ws;                   ws += 262144 * 4;
    ushort_t* APh  = (ushort_t*)ws;                ws += NEL * 2;
    ushort_t* Ahs  = (ushort_t*)ws;                ws += NEL * 2;
    float*    dsum = (float*)ws;                   ws += 8192 * 4;
    ushort_t* PT_A = (ushort_t*)ws;                ws += PSL * 2;  // UNSCALED T0
    ushort_t* PB1a = (ushort_t*)ws;                ws += PSL * 2;
    ushort_t* PB1b = (ushort_t*)ws;                ws += PSL * 2;
    ushort_t* PB2a = (ushort_t*)ws;                ws += PSL * 2;
    ushort_t* PB2b = (ushort_t*)ws;                ws += PSL * 2;
    unsigned* gmax = (unsigned*)ws;                ws += 512 * 4;
    int*      done = (int*)ws;                     ws += 64 * 4;

    // front GEMMs + A-conversion: 576 blocks
    front_gemms<<<576, 256, 0, stream>>>(x, ew1, eb1, gw0, A, Ahs, xab, PT_A,
                                         dsum, gmax, done);
    edge_scores<<<dim3(136, 1, NB), 256, 0, stream>>>(xab, ew2, eb2, mask,
                                                      APh, dsum);

    // layer 0: single-P (unscaled T0, scaleP=1), emits PB1 slices
    fused_layer<<<dim3(32, 2, NB), 256, 0, stream>>>(
        Ahs, APh, PT_A, PT_A, PB1a, PB1b, dsum, gb0, mask, gw1,
        gmax, done, fcw, fcb, out, 0, 0, 1);
    // layer 1: dual-P (PB1), emits PB2 slices
    fused_layer<<<dim3(32, 2, NB), 256, 0, stream>>>(
        Ahs, APh, PB1a, PB1b, PB2a, PB2b, dsum, gb1, mask, gw2,
        gmax, done, fcw, fcb, out, 1, 0, 0);
    // layer 2: dual-P (PB2), final max-pool + FC
    fused_layer<<<dim3(32, 2, NB), 256, 0, stream>>>(
        Ahs, APh, PB2a, PB2b, PB2a, PB2b, dsum, gb2, mask, gw2,
        gmax, done, fcw, fcb, out, 1, 1, 0);
}

// Round 7
// 151.163 us; speedup vs baseline: 1.1457x; 1.0106x over previous
//
#include <hip/hip_runtime.h>
#include <hip/hip_bf16.h>
#include <math.h>

#define NB 8
#define NN 512
#define NC 256
#define HID 32

typedef __attribute__((ext_vector_type(8))) short short8;
typedef __attribute__((ext_vector_type(4))) float float4v;
typedef unsigned short ushort_t;

__device__ __forceinline__ ushort_t f2bf(float x) {
    unsigned u = __float_as_uint(x);
    return (ushort_t)((u + 0x7fffu + ((u >> 16) & 1u)) >> 16);
}
__device__ __forceinline__ float bf2f(ushort_t h) {
    return __uint_as_float(((unsigned)h) << 16);
}

// ---------------------------------------------------------------------------
// Kernel 1: front_gemms, 576 blocks. (verbatim r6)
//   blocks [0,256):   xab = x @ [wa|wb] (+eb1); zero AP-dsum/gmax/done.
//   blocks [256,512): T0  = (x @ gw0)^T bf16, UNSCALED (d-scaling in L0).
//   blocks [512,576): A -> bf16 (Ah) + A col sums -> dsum (direct, no atomics).
// ---------------------------------------------------------------------------
__global__ __launch_bounds__(256) void front_gemms(
    const float* __restrict__ x, const float* __restrict__ ew1,
    const float* __restrict__ eb1, const float* __restrict__ gw0,
    const float* __restrict__ A, ushort_t* __restrict__ Ah,
    float* __restrict__ xab, ushort_t* __restrict__ T0,
    float* __restrict__ dsum, unsigned* __restrict__ gmax, int* __restrict__ done)
{
    __shared__ __align__(16) union {
        struct { float sX[2][32][17]; float sW[2][32][68]; } a;
        struct { float sH[2][32][17]; float sW[2][32][132]; ushort_t sTh[128][24]; } b;
    } u;
    __shared__ float sCol[4][64];
    int t = threadIdx.x;

    if (blockIdx.x < 256) {
        // ---- role A: xab = x @ [wa|wb]
        if (blockIdx.x < 16) dsum[(NB * NN) + blockIdx.x * 256 + t] = 0.f;  // AP half only
        if (blockIdx.x == 16) {
            gmax[t] = 0u; gmax[t + 256] = 0u;
            if (t < NB) done[t] = 0;
        }
        int r0 = blockIdx.x * 16;
        int tx = t & 15, ty = t >> 4;
        int xk = (t & 15) * 2, xr = t >> 4;
        int c4 = (t & 15) * 4;
        int whalf = c4 >> 5, wcc = c4 & 31;
        float acc[4] = {0.f, 0.f, 0.f, 0.f};

        float2 rx = *(const float2*)(x + (size_t)(r0 + xr) * NC + xk);
        float4 rw0 = *(const float4*)(ew1 + (size_t)(whalf * NC + xr) * HID + wcc);
        float4 rw1 = *(const float4*)(ew1 + (size_t)(whalf * NC + xr + 16) * HID + wcc);

        for (int k0 = 0; k0 < NC; k0 += 32) {
            int cur = (k0 >> 5) & 1;
            u.a.sX[cur][xk][xr] = rx.x; u.a.sX[cur][xk + 1][xr] = rx.y;
            *(float4*)&u.a.sW[cur][xr][c4] = rw0;
            *(float4*)&u.a.sW[cur][xr + 16][c4] = rw1;
            if (k0 + 32 < NC) {
                rx  = *(const float2*)(x + (size_t)(r0 + xr) * NC + k0 + 32 + xk);
                rw0 = *(const float4*)(ew1 + (size_t)(whalf * NC + k0 + 32 + xr) * HID + wcc);
                rw1 = *(const float4*)(ew1 + (size_t)(whalf * NC + k0 + 32 + xr + 16) * HID + wcc);
            }
            __syncthreads();
#pragma unroll
            for (int k = 0; k < 32; ++k) {
                float a = u.a.sX[cur][k][ty];
                float4 w = *(const float4*)&u.a.sW[cur][k][tx * 4];
                acc[0] = fmaf(a, w.x, acc[0]); acc[1] = fmaf(a, w.y, acc[1]);
                acc[2] = fmaf(a, w.z, acc[2]); acc[3] = fmaf(a, w.w, acc[3]);
            }
        }
        int oc4 = tx * 4;
        float4 o; o.x = acc[0]; o.y = acc[1]; o.z = acc[2]; o.w = acc[3];
        if (oc4 >= 32) {
            o.x += eb1[oc4 - 32]; o.y += eb1[oc4 - 31];
            o.z += eb1[oc4 - 30]; o.w += eb1[oc4 - 29];
        }
        *(float4*)&xab[(size_t)(r0 + ty) * 64 + oc4] = o;
    } else if (blockIdx.x < 512) {
        // ---- role B: T0 = (x @ gw0)^T, unscaled bf16
        int r0 = (blockIdx.x - 256) * 16;
        int tx = t & 31, ty = t >> 5;
        int xk = (t & 15) * 2, xr = t >> 4;
        int c4w = (t & 31) * 4;
        int whalf = c4w >> 6, wcc = c4w & 63;
        int wk = t >> 5;
        float acc0[4] = {0.f, 0.f, 0.f, 0.f};
        float acc1[4] = {0.f, 0.f, 0.f, 0.f};

        float2 rx = *(const float2*)(x + (size_t)(r0 + xr) * NC + xk);
        float4 rw[4];
#pragma unroll
        for (int rr = 0; rr < 4; ++rr)
            rw[rr] = *(const float4*)(gw0 + (size_t)(whalf * NC + wk + rr * 8) * 64 + wcc);

        for (int k0 = 0; k0 < NC; k0 += 32) {
            int cur = (k0 >> 5) & 1;
            u.b.sH[cur][xk][xr] = rx.x; u.b.sH[cur][xk + 1][xr] = rx.y;
#pragma unroll
            for (int rr = 0; rr < 4; ++rr)
                *(float4*)&u.b.sW[cur][wk + rr * 8][c4w] = rw[rr];
            if (k0 + 32 < NC) {
                rx = *(const float2*)(x + (size_t)(r0 + xr) * NC + k0 + 32 + xk);
#pragma unroll
                for (int rr = 0; rr < 4; ++rr)
                    rw[rr] = *(const float4*)(gw0 + (size_t)(whalf * NC + k0 + 32 + wk + rr * 8) * 64 + wcc);
            }
            __syncthreads();
#pragma unroll
            for (int k = 0; k < 32; ++k) {
                float a0 = u.b.sH[cur][k][ty * 2];
                float a1 = u.b.sH[cur][k][ty * 2 + 1];
                float4 w = *(const float4*)&u.b.sW[cur][k][tx * 4];
                acc0[0] = fmaf(a0, w.x, acc0[0]); acc0[1] = fmaf(a0, w.y, acc0[1]);
                acc0[2] = fmaf(a0, w.z, acc0[2]); acc0[3] = fmaf(a0, w.w, acc0[3]);
                acc1[0] = fmaf(a1, w.x, acc1[0]); acc1[1] = fmaf(a1, w.y, acc1[1]);
                acc1[2] = fmaf(a1, w.z, acc1[2]); acc1[3] = fmaf(a1, w.w, acc1[3]);
            }
        }
        __syncthreads();
        int c4 = tx * 4;
#pragma unroll
        for (int r = 0; r < 2; ++r) {
            int rl = ty * 2 + r;
            float* ap = (r == 0) ? acc0 : acc1;
#pragma unroll
            for (int n = 0; n < 4; ++n)
                u.b.sTh[c4 + n][rl] = f2bf(ap[n]);
        }
        __syncthreads();
        {
            int c = t & 127, half = t >> 7;
            int bb = r0 >> 9, ibase = r0 & (NN - 1);
            ushort_t* dst = T0 + ((size_t)(bb * 128 + c)) * NN + ibase + half * 8;
            *(short8*)dst = *(const short8*)&u.b.sTh[c][half * 8];
        }
    } else {
        // ---- role C: A -> bf16 + direct col sums (single writer per col)
        int c = blockIdx.x - 512;         // 0..63
        int b = c >> 3, q = c & 7;        // batch, column-group of 64
        int col = q * 64 + (t & 63);
        int r0 = t >> 6;                  // 0..3
        const float* Ab = A + (size_t)b * NN * NN;
        ushort_t* Hb = Ah + (size_t)b * NN * NN;
        float s = 0.f;
        for (int it = 0; it < 128; ++it) {
            int row = r0 + 4 * it;
            float a = Ab[(size_t)row * NN + col];
            Hb[(size_t)row * NN + col] = f2bf(a);
            s += a;
        }
        sCol[r0][t & 63] = s;
        __syncthreads();
        if (t < 64)
            dsum[b * NN + q * 64 + t] =
                sCol[0][t] + sCol[1][t] + sCol[2][t] + sCol[3][t];
    }
}

// ---------------------------------------------------------------------------
// Kernel 2: edge scores -> AP bf16 + AP col sums (atomic). (verbatim r6)
// ---------------------------------------------------------------------------
__global__ __launch_bounds__(256) void edge_scores(
    const float* __restrict__ xab, const float* __restrict__ ew2,
    const float* __restrict__ eb2, const float* __restrict__ mask,
    ushort_t* __restrict__ APh, float* __restrict__ dsum)
{
    __shared__ __align__(16) float sI[32][68], sJ[32][68];
    __shared__ float sV[32][33];
    int b = blockIdx.z;
    int p = blockIdx.x;
    int X = 0;
    while ((X + 1) * 16 - ((X + 1) * X) / 2 <= p) ++X;
    int Y = X + (p - (X * 16 - (X * (X - 1)) / 2));
    int i0 = X * 32, j0 = Y * 32;
    int t = threadIdx.x;
    int tj = t & 31;

    float4 rW[8];
#pragma unroll
    for (int k4 = 0; k4 < 8; ++k4) rW[k4] = *(const float4*)(ew2 + k4 * 4);
    float eb2v = eb2[0];

    {
        int c4 = (t & 15) * 4;
#pragma unroll
        for (int rr = 0; rr < 2; ++rr) {
            int r = (t >> 4) + rr * 16;
            float4 vi = *(const float4*)(xab + ((size_t)(b * NN + i0 + r)) * 64 + c4);
            float4 vj = *(const float4*)(xab + ((size_t)(b * NN + j0 + r)) * 64 + c4);
            *(float4*)&sI[r][c4] = vi;
            *(float4*)&sJ[r][c4] = vj;
        }
    }
    __syncthreads();

    float rJlo[32], rJhi[32];
#pragma unroll
    for (int k4 = 0; k4 < 8; ++k4) {
        float4 a4 = *(const float4*)&sJ[tj][k4 * 4];
        float4 b4 = *(const float4*)&sJ[tj][32 + k4 * 4];
        rJlo[k4 * 4 + 0] = a4.x; rJlo[k4 * 4 + 1] = a4.y;
        rJlo[k4 * 4 + 2] = a4.z; rJlo[k4 * 4 + 3] = a4.w;
        rJhi[k4 * 4 + 0] = b4.x; rJhi[k4 * 4 + 1] = b4.y;
        rJhi[k4 * 4 + 2] = b4.z; rJhi[k4 * 4 + 3] = b4.w;
    }
    float mj = mask[b * NN + j0 + tj];

#pragma unroll
    for (int pz = 0; pz < 4; ++pz) {
        int ti = (t >> 5) + pz * 8;
        float sij = 0.f, sji = 0.f;
#pragma unroll
        for (int k4 = 0; k4 < 8; ++k4) {
            float4 ia = *(const float4*)&sI[ti][k4 * 4];
            float4 ib = *(const float4*)&sI[ti][32 + k4 * 4];
            float4 wv = rW[k4];
            sij = fmaf(fmaxf(ia.x + rJhi[k4 * 4 + 0], 0.f), wv.x, sij);
            sji = fmaf(fmaxf(rJlo[k4 * 4 + 0] + ib.x, 0.f), wv.x, sji);
            sij = fmaf(fmaxf(ia.y + rJhi[k4 * 4 + 1], 0.f), wv.y, sij);
            sji = fmaf(fmaxf(rJlo[k4 * 4 + 1] + ib.y, 0.f), wv.y, sji);
            sij = fmaf(fmaxf(ia.z + rJhi[k4 * 4 + 2], 0.f), wv.z, sij);
            sji = fmaf(fmaxf(rJlo[k4 * 4 + 2] + ib.z, 0.f), wv.z, sji);
            sij = fmaf(fmaxf(ia.w + rJhi[k4 * 4 + 3], 0.f), wv.w, sij);
            sji = fmaf(fmaxf(rJlo[k4 * 4 + 3] + ib.w, 0.f), wv.w, sji);
        }
        int i = i0 + ti, j = j0 + tj;
        bool ok = (i != j) && (mask[b * NN + i] > 0.f) && (mj > 0.f);
        sV[ti][tj] = ok ? expf(0.5f * (sij + sji) + eb2v) : 0.f;
    }
    __syncthreads();
#pragma unroll
    for (int pz = 0; pz < 4; ++pz) {
        int r = (t >> 5) + pz * 8, c = t & 31;
        size_t o1 = ((size_t)(b * NN + i0 + r)) * NN + j0 + c;
        size_t o2 = ((size_t)(b * NN + j0 + r)) * NN + i0 + c;
        APh[o1] = f2bf(sV[r][c]);
        APh[o2] = f2bf(sV[c][r]);
    }
    if (t < 32) {
        float s = 0.f;
#pragma unroll
        for (int r = 0; r < 32; ++r) s += sV[r][t];
        atomicAdd(&dsum[(NB * NN) + b * NN + j0 + t], s);
    } else if (t < 64 && X != Y) {
        int c = t - 32;
        float s = 0.f;
#pragma unroll
        for (int j = 0; j < 32; ++j) s += sV[c][j];
        atomicAdd(&dsum[(NB * NN) + b * NN + i0 + c], s);
    }
}

// ---------------------------------------------------------------------------
// Kernel 3/4/5: fused layer, grid (32, 2, NB) = 512 blocks (2/CU).
// Phase A: LDS double-buffer + DEPTH-2 register prefetch (each global load
//   gets ~2 iterations to land; LDS ping-pong timing unchanged from r6).
// Phase B gwN weights prefetched into registers BEFORE phase A.
// scaleP=1 applies d_j during staging (layer 0, unscaled T0 input).
// ---------------------------------------------------------------------------
__global__ __launch_bounds__(256) void fused_layer(
    const ushort_t* __restrict__ Ah, const ushort_t* __restrict__ APh,
    const ushort_t* __restrict__ Pa, const ushort_t* __restrict__ Pb,
    ushort_t* __restrict__ Qa, ushort_t* __restrict__ Qb,
    const float* __restrict__ dsum, const float* __restrict__ gb,
    const float* __restrict__ mask, const float* __restrict__ gwN,
    unsigned* __restrict__ gmax, int* __restrict__ done,
    const float* __restrict__ fcw, const float* __restrict__ fcb,
    float* __restrict__ out, int dualP, int mode, int scaleP)
{
    __shared__ union {
        struct {
            ushort_t sA[2][2][16][72];
            ushort_t sP1[2][64][72];
            ushort_t sP2[2][64][72];
        } a;
        struct { ushort_t sWT[128][40]; } b;    // W^T bf16 for phase B
    } u;
    __shared__ float sRed[2][32][17];
    __shared__ float sH16[16][36];
    __shared__ float sD[2][16];
    __shared__ __align__(16) float sDj[2][NN];
    __shared__ int lastFlag;

    int t = threadIdx.x;
    int b = blockIdx.z, ch = blockIdx.y, i0 = blockIdx.x * 16;
    int lane = t & 63, w = t >> 6;
    int quad = lane >> 4, m16 = lane & 15;
    int lap = w >> 1, cg = w & 1;

    // d_j table for layer-0 staging scale (both laplacians, all 512 cols)
    if (scaleP) {
#pragma unroll
        for (int s = 0; s < 4; ++s) {
            int idx = t + s * 256;
            int lp = idx >> 9, j = idx & (NN - 1);
            sDj[lp][j] = rsqrtf(dsum[lp * (NB * NN) + b * NN + j] + 1.0f + 1e-5f);
        }
    }

    // ---- phase A setup
    int sa_arr = t >> 7, sa_id = t & 127;
    int sa_r = sa_id >> 3, sa_q = sa_id & 7;
    const ushort_t* sa_src = (sa_arr ? APh : Ah)
        + ((size_t)(b * NN + i0 + sa_r)) * NN + sa_q * 8;
    int pl0 = t >> 3, pq = t & 7;
    size_t poff0 = ((size_t)(b * 128 + ch * 32 + pl0)) * NN + pq * 8;
    size_t poff1 = ((size_t)(b * 128 + 64 + ch * 32 + pl0)) * NN + pq * 8;

    // prefetch epilogue operands (hidden under the K-loop)
    int gi = b * NN + i0 + m16;
    float dspre = dsum[lap * (NB * NN) + gi];
    int cbase = cg * 16 + quad * 4;
    size_t pvbase = ((size_t)(b * 128 + lap * 64 + ch * 32 + cbase)) * NN + i0 + m16;
    ushort_t pvA[4], pvB[4];
#pragma unroll
    for (int r = 0; r < 4; ++r) {
        pvA[r] = Pa[pvbase + (size_t)r * NN];
        pvB[r] = dualP ? Pb[pvbase + (size_t)r * NN] : (ushort_t)0;
    }

    // prefetch phase-B weights into registers (hidden under the K-loop)
    float gwPre[16];
    if (mode == 0) {
#pragma unroll
        for (int kk = 0; kk < 8; ++kk) {
            int chunk = t + kk * 256;
            int c = chunk & 127;
            int k = (chunk >> 7) * 2;
            int base = (c < 64) ? (ch * 32) : (64 + ch * 32);
            int gc = c & 63;
            gwPre[kk * 2]     = gwN[(size_t)(base + k) * 64 + gc];
            gwPre[kk * 2 + 1] = gwN[(size_t)(base + k + 1) * 64 + gc];
        }
    }

    float4v acc = {0.f, 0.f, 0.f, 0.f};

    // depth-2 register prefetch: two register sets, LDS ping-pong as before
    short8 A0, P1a0, P1b0, P2a0, P2b0;
    short8 A1, P1a1, P1b1, P2a1, P2b1;

    A0   = *(const short8*)(sa_src);
    P1a0 = *(const short8*)(Pa + poff0);
    P1b0 = *(const short8*)(Pa + poff1);
    A1   = *(const short8*)(sa_src + 64);
    P1a1 = *(const short8*)(Pa + poff0 + 64);
    P1b1 = *(const short8*)(Pa + poff1 + 64);
    P2a0 = P1a0; P2b0 = P1b0; P2a1 = P1a1; P2b1 = P1b1;
    if (dualP) {
        P2a0 = *(const short8*)(Pb + poff0);
        P2b0 = *(const short8*)(Pb + poff1);
        P2a1 = *(const short8*)(Pb + poff0 + 64);
        P2b1 = *(const short8*)(Pb + poff1 + 64);
    }
    __syncthreads();   // sDj visible before first staging use (scaleP)

#pragma unroll
    for (int i = 0; i < 8; ++i) {
        int k0 = i * 64;
        int cur = i & 1;
        short8 rA   = cur ? A1   : A0;
        short8 rP1a = cur ? P1a1 : P1a0;
        short8 rP1b = cur ? P1b1 : P1b0;
        short8 rP2a = cur ? P2a1 : P2a0;
        short8 rP2b = cur ? P2b1 : P2b0;

        *(short8*)&u.a.sA[cur][sa_arr][sa_r][sa_q * 8] = rA;
        if (scaleP) {
            float4v d0a = *(const float4v*)&sDj[0][k0 + pq * 8];
            float4v d0b = *(const float4v*)&sDj[0][k0 + pq * 8 + 4];
            float4v d1a = *(const float4v*)&sDj[1][k0 + pq * 8];
            float4v d1b = *(const float4v*)&sDj[1][k0 + pq * 8 + 4];
            short8 w0, w1;
#pragma unroll
            for (int e = 0; e < 4; ++e) {
                w0[e]     = (short)f2bf(bf2f((ushort_t)rP1a[e])     * d0a[e]);
                w0[e + 4] = (short)f2bf(bf2f((ushort_t)rP1a[e + 4]) * d0b[e]);
                w1[e]     = (short)f2bf(bf2f((ushort_t)rP1b[e])     * d1a[e]);
                w1[e + 4] = (short)f2bf(bf2f((ushort_t)rP1b[e + 4]) * d1b[e]);
            }
            *(short8*)&u.a.sP1[cur][pl0][pq * 8] = w0;
            *(short8*)&u.a.sP1[cur][32 + pl0][pq * 8] = w1;
        } else {
            *(short8*)&u.a.sP1[cur][pl0][pq * 8] = rP1a;
            *(short8*)&u.a.sP1[cur][32 + pl0][pq * 8] = rP1b;
            if (dualP) {
                *(short8*)&u.a.sP2[cur][pl0][pq * 8] = rP2a;
                *(short8*)&u.a.sP2[cur][32 + pl0][pq * 8] = rP2b;
            }
        }
        if (i + 2 < 8) {
            int kn = k0 + 128;
            if (cur == 0) {
                A0   = *(const short8*)(sa_src + kn);
                P1a0 = *(const short8*)(Pa + poff0 + kn);
                P1b0 = *(const short8*)(Pa + poff1 + kn);
                if (dualP) {
                    P2a0 = *(const short8*)(Pb + poff0 + kn);
                    P2b0 = *(const short8*)(Pb + poff1 + kn);
                }
            } else {
                A1   = *(const short8*)(sa_src + kn);
                P1a1 = *(const short8*)(Pa + poff0 + kn);
                P1b1 = *(const short8*)(Pa + poff1 + kn);
                if (dualP) {
                    P2a1 = *(const short8*)(Pb + poff0 + kn);
                    P2b1 = *(const short8*)(Pb + poff1 + kn);
                }
            }
        }
        __syncthreads();
#pragma unroll
        for (int kh = 0; kh < 2; ++kh) {
            int ko = kh * 32 + quad * 8;
            short8 av = *(const short8*)&u.a.sA[cur][lap][m16][ko];
            short8 p1 = *(const short8*)&u.a.sP1[cur][w * 16 + m16][ko];
            acc = __builtin_amdgcn_mfma_f32_16x16x32_bf16(p1, av, acc, 0, 0, 0);
            if (dualP) {
                short8 p2 = *(const short8*)&u.a.sP2[cur][w * 16 + m16][ko];
                acc = __builtin_amdgcn_mfma_f32_16x16x32_bf16(p2, av, acc, 0, 0, 0);
            }
        }
    }
    // epilogue -> sRed, capture d into sD
    float d = rsqrtf(dspre + 1.0f + 1e-5f);
    if (cg == 0 && quad == 0) sD[lap][m16] = d;
#pragma unroll
    for (int r = 0; r < 4; ++r) {
        int c32 = cbase + r;
        float pv = bf2f(pvA[r]);
        if (dualP) pv += bf2f(pvB[r]);
        if (scaleP) pv *= d;
        sRed[lap][c32][m16] = d * (acc[r] + pv);
    }
    __syncthreads();
    // combine laps + bias + mask + relu -> sH16
#pragma unroll
    for (int s = 0; s < 2; ++s) {
        int idx = t + s * 256;
        int c32 = idx & 31, i = idx >> 5;
        float mv = mask[b * NN + i0 + i];
        float v = (sRed[0][c32][i] + sRed[1][c32][i] + gb[ch * 32 + c32]) * mv;
        sH16[i][c32] = fmaxf(v, 0.f);
    }
    __syncthreads();

    if (mode == 0) {
        // ---- phase B: partial pre for next layer via MFMA, K=32
#pragma unroll
        for (int kk = 0; kk < 8; ++kk) {
            int chunk = t + kk * 256;            // 0..2047
            int c = chunk & 127;
            int k = (chunk >> 7) * 2;            // even k
            unsigned pk = (unsigned)f2bf(gwPre[kk * 2])
                        | ((unsigned)f2bf(gwPre[kk * 2 + 1]) << 16);
            *(unsigned*)&u.b.sWT[c][k] = pk;
        }
        __syncthreads();
        float4 h0 = *(const float4*)&sH16[m16][quad * 8];
        float4 h1 = *(const float4*)&sH16[m16][quad * 8 + 4];
        short8 bfv;
        bfv[0] = f2bf(h0.x); bfv[1] = f2bf(h0.y); bfv[2] = f2bf(h0.z); bfv[3] = f2bf(h0.w);
        bfv[4] = f2bf(h1.x); bfv[5] = f2bf(h1.y); bfv[6] = f2bf(h1.z); bfv[7] = f2bf(h1.w);
        ushort_t* Q = ch ? Qb : Qa;
#pragma unroll
        for (int s2 = 0; s2 < 2; ++s2) {
            int ctile = w * 2 + s2;              // 0..7
            short8 af = *(const short8*)&u.b.sWT[ctile * 16 + m16][quad * 8];
            float4v dacc = {0.f, 0.f, 0.f, 0.f};
            dacc = __builtin_amdgcn_mfma_f32_16x16x32_bf16(af, bfv, dacc, 0, 0, 0);
            float dsc = sD[(ctile >= 4) ? 1 : 0][m16];
#pragma unroll
            for (int r = 0; r < 4; ++r) {
                int c = ctile * 16 + quad * 4 + r;
                Q[((size_t)(b * 128 + c)) * NN + i0 + m16] = f2bf(dsc * dacc[r]);
            }
        }
    } else {
        // ---- phase C: max-pool + FC
        if (t < 32) {
            float mx = 0.f;
#pragma unroll
            for (int r = 0; r < 16; ++r) mx = fmaxf(mx, sH16[r][t]);
            atomicMax(&gmax[b * 64 + ch * 32 + t], __float_as_uint(mx));
        }
        __syncthreads();
        if (t == 0) {
            __threadfence();
            int old = atomicAdd(&done[b], 1);
            lastFlag = (old == 63);
        }
        __syncthreads();
        if (lastFlag) {
            if (t < 64) {
                unsigned ub = __hip_atomic_load(&gmax[b * 64 + t],
                                                __ATOMIC_RELAXED,
                                                __HIP_MEMORY_SCOPE_AGENT);
                ((float*)sRed)[t] = __uint_as_float(ub);
            }
            __syncthreads();
            if (t < 2) {
                float a2 = fcb[t];
#pragma unroll
                for (int k = 0; k < 64; ++k)
                    a2 = fmaf(((float*)sRed)[k], fcw[k * 2 + t], a2);
                out[b * 2 + t] = a2;
            }
        }
    }
}

extern "C" void kernel_launch(void* const* d_in, const int* in_sizes, int n_in,
                              void* d_out, int out_size, void* d_ws, size_t ws_size,
                              hipStream_t stream)
{
    const float* x    = (const float*)d_in[0];
    const float* A    = (const float*)d_in[1];
    const float* mask = (const float*)d_in[2];
    const float* ew1  = (const float*)d_in[3];
    const float* eb1  = (const float*)d_in[4];
    const float* ew2  = (const float*)d_in[5];
    const float* eb2  = (const float*)d_in[6];
    const float* gw0  = (const float*)d_in[7];
    const float* gb0  = (const float*)d_in[8];
    const float* gw1  = (const float*)d_in[9];
    const float* gb1  = (const float*)d_in[10];
    const float* gw2  = (const float*)d_in[11];
    const float* gb2  = (const float*)d_in[12];
    const float* fcw  = (const float*)d_in[13];
    const float* fcb  = (const float*)d_in[14];
    float* out = (float*)d_out;
    char* ws = (char*)d_ws;

    const size_t NEL = (size_t)NB * NN * NN;      // 2,097,152
    const size_t PSL = (size_t)NB * 128 * NN;     // 524,288 (one P slice)
    float*    xab  = (float*)ws;                   ws += 262144 * 4;
    ushort_t* APh  = (ushort_t*)ws;                ws += NEL * 2;
    ushort_t* Ahs  = (ushort_t*)ws;                ws += NEL * 2;
    float*    dsum = (float*)ws;                   ws += 8192 * 4;
    ushort_t* PT_A = (ushort_t*)ws;                ws += PSL * 2;  // UNSCALED T0
    ushort_t* PB1a = (ushort_t*)ws;                ws += PSL * 2;
    ushort_t* PB1b = (ushort_t*)ws;                ws += PSL * 2;
    ushort_t* PB2a = (ushort_t*)ws;                ws += PSL * 2;
    ushort_t* PB2b = (ushort_t*)ws;                ws += PSL * 2;
    unsigned* gmax = (unsigned*)ws;                ws += 512 * 4;
    int*      done = (int*)ws;                     ws += 64 * 4;

    // front GEMMs + A-conversion: 576 blocks
    front_gemms<<<576, 256, 0, stream>>>(x, ew1, eb1, gw0, A, Ahs, xab, PT_A,
                                         dsum, gmax, done);
    edge_scores<<<dim3(136, 1, NB), 256, 0, stream>>>(xab, ew2, eb2, mask,
                                                      APh, dsum);

    // layer 0: single-P (unscaled T0, scaleP=1), emits PB1 slices
    fused_layer<<<dim3(32, 2, NB), 256, 0, stream>>>(
        Ahs, APh, PT_A, PT_A, PB1a, PB1b, dsum, gb0, mask, gw1,
        gmax, done, fcw, fcb, out, 0, 0, 1);
    // layer 1: dual-P (PB1), emits PB2 slices
    fused_layer<<<dim3(32, 2, NB), 256, 0, stream>>>(
        Ahs, APh, PB1a, PB1b, PB2a, PB2b, dsum, gb1, mask, gw2,
        gmax, done, fcw, fcb, out, 1, 0, 0);
    // layer 2: dual-P (PB2), final max-pool + FC
    fused_layer<<<dim3(32, 2, NB), 256, 0, stream>>>(
        Ahs, APh, PB2a, PB2b, PB2a, PB2b, dsum, gb2, mask, gw2,
        gmax, done, fcw, fcb, out, 1, 1, 0);
}

// Round 9
// 149.570 us; speedup vs baseline: 1.1579x; 1.0106x over previous
//
#include <hip/hip_runtime.h>
#include <hip/hip_bf16.h>
#include <math.h>

#define NB 8
#define NN 512
#define NC 256
#define HID 32

typedef __attribute__((ext_vector_type(8))) short short8;
typedef __attribute__((ext_vector_type(4))) float float4v;
typedef unsigned short ushort_t;

__device__ __forceinline__ ushort_t f2bf(float x) {
    unsigned u = __float_as_uint(x);
    return (ushort_t)((u + 0x7fffu + ((u >> 16) & 1u)) >> 16);
}
__device__ __forceinline__ float bf2f(ushort_t h) {
    return __uint_as_float(((unsigned)h) << 16);
}

// ---------------------------------------------------------------------------
// Kernel 1: xaxb_gemm, 256 blocks (1/CU). ONLY the xab GEMM + zeroing —
// T0/A-conv moved to kernel 2 (they don't gate edge_scores).
// Register-prefetch + LDS double-buffer, one barrier per K-step.
// ---------------------------------------------------------------------------
__global__ __launch_bounds__(256) void xaxb_gemm(
    const float* __restrict__ x, const float* __restrict__ ew1,
    const float* __restrict__ eb1, float* __restrict__ xab,
    float* __restrict__ dsum, unsigned* __restrict__ gmax, int* __restrict__ done)
{
    __shared__ __align__(16) struct { float sX[2][32][17]; float sW[2][32][68]; } u;
    int t = threadIdx.x;

    if (blockIdx.x < 16) dsum[(NB * NN) + blockIdx.x * 256 + t] = 0.f;  // AP half
    if (blockIdx.x == 16) {
        gmax[t] = 0u; gmax[t + 256] = 0u;
        if (t < NB) done[t] = 0;
    }
    int r0 = blockIdx.x * 16;
    int tx = t & 15, ty = t >> 4;
    int xk = (t & 15) * 2, xr = t >> 4;
    int c4 = (t & 15) * 4;
    int whalf = c4 >> 5, wcc = c4 & 31;
    float acc[4] = {0.f, 0.f, 0.f, 0.f};

    float2 rx = *(const float2*)(x + (size_t)(r0 + xr) * NC + xk);
    float4 rw0 = *(const float4*)(ew1 + (size_t)(whalf * NC + xr) * HID + wcc);
    float4 rw1 = *(const float4*)(ew1 + (size_t)(whalf * NC + xr + 16) * HID + wcc);

    for (int k0 = 0; k0 < NC; k0 += 32) {
        int cur = (k0 >> 5) & 1;
        u.sX[cur][xk][xr] = rx.x; u.sX[cur][xk + 1][xr] = rx.y;
        *(float4*)&u.sW[cur][xr][c4] = rw0;
        *(float4*)&u.sW[cur][xr + 16][c4] = rw1;
        if (k0 + 32 < NC) {
            rx  = *(const float2*)(x + (size_t)(r0 + xr) * NC + k0 + 32 + xk);
            rw0 = *(const float4*)(ew1 + (size_t)(whalf * NC + k0 + 32 + xr) * HID + wcc);
            rw1 = *(const float4*)(ew1 + (size_t)(whalf * NC + k0 + 32 + xr + 16) * HID + wcc);
        }
        __syncthreads();
#pragma unroll
        for (int k = 0; k < 32; ++k) {
            float a = u.sX[cur][k][ty];
            float4 w = *(const float4*)&u.sW[cur][k][tx * 4];
            acc[0] = fmaf(a, w.x, acc[0]); acc[1] = fmaf(a, w.y, acc[1]);
            acc[2] = fmaf(a, w.z, acc[2]); acc[3] = fmaf(a, w.w, acc[3]);
        }
    }
    int oc4 = tx * 4;
    float4 o; o.x = acc[0]; o.y = acc[1]; o.z = acc[2]; o.w = acc[3];
    if (oc4 >= 32) {
        o.x += eb1[oc4 - 32]; o.y += eb1[oc4 - 31];
        o.z += eb1[oc4 - 30]; o.w += eb1[oc4 - 29];
    }
    *(float4*)&xab[(size_t)(r0 + ty) * 64 + oc4] = o;
}

// ---------------------------------------------------------------------------
// Kernel 2: edge_plus, 1408 blocks (~26KB LDS -> 6/CU, single dispatch round).
//   blocks [0,256):    role B — T0 = (x @ gw0)^T bf16 (single-buffer staging,
//                      register prefetch; needed only by layer 0).
//   blocks [256,320):  role C — A -> bf16 + direct col sums (no atomics).
//   blocks [320,1408): edge scores (needs xab from K1) -> AP bf16 + AP sums.
// Roles B/C overlap with the edge tiles instead of gating them.
// ---------------------------------------------------------------------------
__global__ __launch_bounds__(256) void edge_plus(
    const float* __restrict__ x, const float* __restrict__ gw0,
    const float* __restrict__ A, ushort_t* __restrict__ Ah,
    const float* __restrict__ xab, const float* __restrict__ ew2,
    const float* __restrict__ eb2, const float* __restrict__ mask,
    ushort_t* __restrict__ T0, ushort_t* __restrict__ APh,
    float* __restrict__ dsum)
{
    __shared__ __align__(16) union {
        struct { float sH[32][17]; float sW[32][132]; ushort_t sTh[128][24]; } b;
        struct { float sI[32][68]; float sJ[32][68]; float sV[32][33]; } e;
    } u;
    __shared__ float sCol[4][64];
    int bid = blockIdx.x;
    int t = threadIdx.x;

    if (bid < 256) {
        // ---- role B: T0 = (x @ gw0)^T, unscaled bf16 (single-buffer)
        int r0 = bid * 16;
        int tx = t & 31, ty = t >> 5;
        int xk = (t & 15) * 2, xr = t >> 4;
        int c4w = (t & 31) * 4;
        int whalf = c4w >> 6, wcc = c4w & 63;
        int wk = t >> 5;
        float acc0[4] = {0.f, 0.f, 0.f, 0.f};
        float acc1[4] = {0.f, 0.f, 0.f, 0.f};

        float2 rx = *(const float2*)(x + (size_t)(r0 + xr) * NC + xk);
        float4 rw[4];
#pragma unroll
        for (int rr = 0; rr < 4; ++rr)
            rw[rr] = *(const float4*)(gw0 + (size_t)(whalf * NC + wk + rr * 8) * 64 + wcc);

        for (int k0 = 0; k0 < NC; k0 += 32) {
            u.b.sH[xk][xr] = rx.x; u.b.sH[xk + 1][xr] = rx.y;
#pragma unroll
            for (int rr = 0; rr < 4; ++rr)
                *(float4*)&u.b.sW[wk + rr * 8][c4w] = rw[rr];
            if (k0 + 32 < NC) {
                rx = *(const float2*)(x + (size_t)(r0 + xr) * NC + k0 + 32 + xk);
#pragma unroll
                for (int rr = 0; rr < 4; ++rr)
                    rw[rr] = *(const float4*)(gw0 + (size_t)(whalf * NC + k0 + 32 + wk + rr * 8) * 64 + wcc);
            }
            __syncthreads();
#pragma unroll
            for (int k = 0; k < 32; ++k) {
                float a0 = u.b.sH[k][ty * 2];
                float a1 = u.b.sH[k][ty * 2 + 1];
                float4 w = *(const float4*)&u.b.sW[k][tx * 4];
                acc0[0] = fmaf(a0, w.x, acc0[0]); acc0[1] = fmaf(a0, w.y, acc0[1]);
                acc0[2] = fmaf(a0, w.z, acc0[2]); acc0[3] = fmaf(a0, w.w, acc0[3]);
                acc1[0] = fmaf(a1, w.x, acc1[0]); acc1[1] = fmaf(a1, w.y, acc1[1]);
                acc1[2] = fmaf(a1, w.z, acc1[2]); acc1[3] = fmaf(a1, w.w, acc1[3]);
            }
            __syncthreads();
        }
        int c4 = tx * 4;
#pragma unroll
        for (int r = 0; r < 2; ++r) {
            int rl = ty * 2 + r;
            float* ap = (r == 0) ? acc0 : acc1;
#pragma unroll
            for (int n = 0; n < 4; ++n)
                u.b.sTh[c4 + n][rl] = f2bf(ap[n]);
        }
        __syncthreads();
        {
            int c = t & 127, half = t >> 7;
            int bb = r0 >> 9, ibase = r0 & (NN - 1);
            ushort_t* dst = T0 + ((size_t)(bb * 128 + c)) * NN + ibase + half * 8;
            *(short8*)dst = *(const short8*)&u.b.sTh[c][half * 8];
        }
    } else if (bid < 320) {
        // ---- role C: A -> bf16 + direct col sums (single writer per col)
        int c = bid - 256;                // 0..63
        int b = c >> 3, q = c & 7;        // batch, column-group of 64
        int col = q * 64 + (t & 63);
        int r0 = t >> 6;                  // 0..3
        const float* Ab = A + (size_t)b * NN * NN;
        ushort_t* Hb = Ah + (size_t)b * NN * NN;
        float s = 0.f;
        for (int it = 0; it < 128; ++it) {
            int row = r0 + 4 * it;
            float a = Ab[(size_t)row * NN + col];
            Hb[(size_t)row * NN + col] = f2bf(a);
            s += a;
        }
        sCol[r0][t & 63] = s;
        __syncthreads();
        if (t < 64)
            dsum[b * NN + q * 64 + t] =
                sCol[0][t] + sCol[1][t] + sCol[2][t] + sCol[3][t];
    } else {
        // ---- edge scores (verbatim r7 inner structure)
        int e0 = bid - 320;
        int b = e0 / 136, p = e0 - b * 136;
        int X = 0;
        while ((X + 1) * 16 - ((X + 1) * X) / 2 <= p) ++X;
        int Y = X + (p - (X * 16 - (X * (X - 1)) / 2));
        int i0 = X * 32, j0 = Y * 32;
        int tj = t & 31;

        float4 rW[8];
#pragma unroll
        for (int k4 = 0; k4 < 8; ++k4) rW[k4] = *(const float4*)(ew2 + k4 * 4);
        float eb2v = eb2[0];

        {
            int c4 = (t & 15) * 4;
#pragma unroll
            for (int rr = 0; rr < 2; ++rr) {
                int r = (t >> 4) + rr * 16;
                float4 vi = *(const float4*)(xab + ((size_t)(b * NN + i0 + r)) * 64 + c4);
                float4 vj = *(const float4*)(xab + ((size_t)(b * NN + j0 + r)) * 64 + c4);
                *(float4*)&u.e.sI[r][c4] = vi;
                *(float4*)&u.e.sJ[r][c4] = vj;
            }
        }
        __syncthreads();

        float rJlo[32], rJhi[32];
#pragma unroll
        for (int k4 = 0; k4 < 8; ++k4) {
            float4 a4 = *(const float4*)&u.e.sJ[tj][k4 * 4];
            float4 b4 = *(const float4*)&u.e.sJ[tj][32 + k4 * 4];
            rJlo[k4 * 4 + 0] = a4.x; rJlo[k4 * 4 + 1] = a4.y;
            rJlo[k4 * 4 + 2] = a4.z; rJlo[k4 * 4 + 3] = a4.w;
            rJhi[k4 * 4 + 0] = b4.x; rJhi[k4 * 4 + 1] = b4.y;
            rJhi[k4 * 4 + 2] = b4.z; rJhi[k4 * 4 + 3] = b4.w;
        }
        float mj = mask[b * NN + j0 + tj];

#pragma unroll
        for (int pz = 0; pz < 4; ++pz) {
            int ti = (t >> 5) + pz * 8;
            float sij = 0.f, sji = 0.f;
#pragma unroll
            for (int k4 = 0; k4 < 8; ++k4) {
                float4 ia = *(const float4*)&u.e.sI[ti][k4 * 4];
                float4 ib = *(const float4*)&u.e.sI[ti][32 + k4 * 4];
                float4 wv = rW[k4];
                sij = fmaf(fmaxf(ia.x + rJhi[k4 * 4 + 0], 0.f), wv.x, sij);
                sji = fmaf(fmaxf(rJlo[k4 * 4 + 0] + ib.x, 0.f), wv.x, sji);
                sij = fmaf(fmaxf(ia.y + rJhi[k4 * 4 + 1], 0.f), wv.y, sij);
                sji = fmaf(fmaxf(rJlo[k4 * 4 + 1] + ib.y, 0.f), wv.y, sji);
                sij = fmaf(fmaxf(ia.z + rJhi[k4 * 4 + 2], 0.f), wv.z, sij);
                sji = fmaf(fmaxf(rJlo[k4 * 4 + 2] + ib.z, 0.f), wv.z, sji);
                sij = fmaf(fmaxf(ia.w + rJhi[k4 * 4 + 3], 0.f), wv.w, sij);
                sji = fmaf(fmaxf(rJlo[k4 * 4 + 3] + ib.w, 0.f), wv.w, sji);
            }
            int i = i0 + ti, j = j0 + tj;
            bool ok = (i != j) && (mask[b * NN + i] > 0.f) && (mj > 0.f);
            u.e.sV[ti][tj] = ok ? expf(0.5f * (sij + sji) + eb2v) : 0.f;
        }
        __syncthreads();
#pragma unroll
        for (int pz = 0; pz < 4; ++pz) {
            int r = (t >> 5) + pz * 8, c = t & 31;
            size_t o1 = ((size_t)(b * NN + i0 + r)) * NN + j0 + c;
            size_t o2 = ((size_t)(b * NN + j0 + r)) * NN + i0 + c;
            APh[o1] = f2bf(u.e.sV[r][c]);
            APh[o2] = f2bf(u.e.sV[c][r]);
        }
        if (t < 32) {
            float s = 0.f;
#pragma unroll
            for (int r = 0; r < 32; ++r) s += u.e.sV[r][t];
            atomicAdd(&dsum[(NB * NN) + b * NN + j0 + t], s);
        } else if (t < 64 && X != Y) {
            int c = t - 32;
            float s = 0.f;
#pragma unroll
            for (int j = 0; j < 32; ++j) s += u.e.sV[c][j];
            atomicAdd(&dsum[(NB * NN) + b * NN + i0 + c], s);
        }
    }
}

// ---------------------------------------------------------------------------
// Kernel 3/4/5: fused layer, grid (32, 2, NB) = 512 blocks (2/CU).
// (verbatim r7: depth-2 register prefetch + LDS dbuf, gwN/pv/dsum hoisted.)
// ---------------------------------------------------------------------------
__global__ __launch_bounds__(256) void fused_layer(
    const ushort_t* __restrict__ Ah, const ushort_t* __restrict__ APh,
    const ushort_t* __restrict__ Pa, const ushort_t* __restrict__ Pb,
    ushort_t* __restrict__ Qa, ushort_t* __restrict__ Qb,
    const float* __restrict__ dsum, const float* __restrict__ gb,
    const float* __restrict__ mask, const float* __restrict__ gwN,
    unsigned* __restrict__ gmax, int* __restrict__ done,
    const float* __restrict__ fcw, const float* __restrict__ fcb,
    float* __restrict__ out, int dualP, int mode, int scaleP)
{
    __shared__ union {
        struct {
            ushort_t sA[2][2][16][72];
            ushort_t sP1[2][64][72];
            ushort_t sP2[2][64][72];
        } a;
        struct { ushort_t sWT[128][40]; } b;    // W^T bf16 for phase B
    } u;
    __shared__ float sRed[2][32][17];
    __shared__ float sH16[16][36];
    __shared__ float sD[2][16];
    __shared__ __align__(16) float sDj[2][NN];
    __shared__ int lastFlag;

    int t = threadIdx.x;
    int b = blockIdx.z, ch = blockIdx.y, i0 = blockIdx.x * 16;
    int lane = t & 63, w = t >> 6;
    int quad = lane >> 4, m16 = lane & 15;
    int lap = w >> 1, cg = w & 1;

    // d_j table for layer-0 staging scale (both laplacians, all 512 cols)
    if (scaleP) {
#pragma unroll
        for (int s = 0; s < 4; ++s) {
            int idx = t + s * 256;
            int lp = idx >> 9, j = idx & (NN - 1);
            sDj[lp][j] = rsqrtf(dsum[lp * (NB * NN) + b * NN + j] + 1.0f + 1e-5f);
        }
    }

    // ---- phase A setup
    int sa_arr = t >> 7, sa_id = t & 127;
    int sa_r = sa_id >> 3, sa_q = sa_id & 7;
    const ushort_t* sa_src = (sa_arr ? APh : Ah)
        + ((size_t)(b * NN + i0 + sa_r)) * NN + sa_q * 8;
    int pl0 = t >> 3, pq = t & 7;
    size_t poff0 = ((size_t)(b * 128 + ch * 32 + pl0)) * NN + pq * 8;
    size_t poff1 = ((size_t)(b * 128 + 64 + ch * 32 + pl0)) * NN + pq * 8;

    // prefetch epilogue operands (hidden under the K-loop)
    int gi = b * NN + i0 + m16;
    float dspre = dsum[lap * (NB * NN) + gi];
    int cbase = cg * 16 + quad * 4;
    size_t pvbase = ((size_t)(b * 128 + lap * 64 + ch * 32 + cbase)) * NN + i0 + m16;
    ushort_t pvA[4], pvB[4];
#pragma unroll
    for (int r = 0; r < 4; ++r) {
        pvA[r] = Pa[pvbase + (size_t)r * NN];
        pvB[r] = dualP ? Pb[pvbase + (size_t)r * NN] : (ushort_t)0;
    }

    // prefetch phase-B weights into registers (hidden under the K-loop)
    float gwPre[16];
    if (mode == 0) {
#pragma unroll
        for (int kk = 0; kk < 8; ++kk) {
            int chunk = t + kk * 256;
            int c = chunk & 127;
            int k = (chunk >> 7) * 2;
            int base = (c < 64) ? (ch * 32) : (64 + ch * 32);
            int gc = c & 63;
            gwPre[kk * 2]     = gwN[(size_t)(base + k) * 64 + gc];
            gwPre[kk * 2 + 1] = gwN[(size_t)(base + k + 1) * 64 + gc];
        }
    }

    float4v acc = {0.f, 0.f, 0.f, 0.f};

    // depth-2 register prefetch: two register sets, LDS ping-pong as before
    short8 A0, P1a0, P1b0, P2a0, P2b0;
    short8 A1, P1a1, P1b1, P2a1, P2b1;

    A0   = *(const short8*)(sa_src);
    P1a0 = *(const short8*)(Pa + poff0);
    P1b0 = *(const short8*)(Pa + poff1);
    A1   = *(const short8*)(sa_src + 64);
    P1a1 = *(const short8*)(Pa + poff0 + 64);
    P1b1 = *(const short8*)(Pa + poff1 + 64);
    P2a0 = P1a0; P2b0 = P1b0; P2a1 = P1a1; P2b1 = P1b1;
    if (dualP) {
        P2a0 = *(const short8*)(Pb + poff0);
        P2b0 = *(const short8*)(Pb + poff1);
        P2a1 = *(const short8*)(Pb + poff0 + 64);
        P2b1 = *(const short8*)(Pb + poff1 + 64);
    }
    __syncthreads();   // sDj visible before first staging use (scaleP)

#pragma unroll
    for (int i = 0; i < 8; ++i) {
        int k0 = i * 64;
        int cur = i & 1;
        short8 rA   = cur ? A1   : A0;
        short8 rP1a = cur ? P1a1 : P1a0;
        short8 rP1b = cur ? P1b1 : P1b0;
        short8 rP2a = cur ? P2a1 : P2a0;
        short8 rP2b = cur ? P2b1 : P2b0;

        *(short8*)&u.a.sA[cur][sa_arr][sa_r][sa_q * 8] = rA;
        if (scaleP) {
            float4v d0a = *(const float4v*)&sDj[0][k0 + pq * 8];
            float4v d0b = *(const float4v*)&sDj[0][k0 + pq * 8 + 4];
            float4v d1a = *(const float4v*)&sDj[1][k0 + pq * 8];
            float4v d1b = *(const float4v*)&sDj[1][k0 + pq * 8 + 4];
            short8 w0, w1;
#pragma unroll
            for (int e = 0; e < 4; ++e) {
                w0[e]     = (short)f2bf(bf2f((ushort_t)rP1a[e])     * d0a[e]);
                w0[e + 4] = (short)f2bf(bf2f((ushort_t)rP1a[e + 4]) * d0b[e]);
                w1[e]     = (short)f2bf(bf2f((ushort_t)rP1b[e])     * d1a[e]);
                w1[e + 4] = (short)f2bf(bf2f((ushort_t)rP1b[e + 4]) * d1b[e]);
            }
            *(short8*)&u.a.sP1[cur][pl0][pq * 8] = w0;
            *(short8*)&u.a.sP1[cur][32 + pl0][pq * 8] = w1;
        } else {
            *(short8*)&u.a.sP1[cur][pl0][pq * 8] = rP1a;
            *(short8*)&u.a.sP1[cur][32 + pl0][pq * 8] = rP1b;
            if (dualP) {
                *(short8*)&u.a.sP2[cur][pl0][pq * 8] = rP2a;
                *(short8*)&u.a.sP2[cur][32 + pl0][pq * 8] = rP2b;
            }
        }
        if (i + 2 < 8) {
            int kn = k0 + 128;
            if (cur == 0) {
                A0   = *(const short8*)(sa_src + kn);
                P1a0 = *(const short8*)(Pa + poff0 + kn);
                P1b0 = *(const short8*)(Pa + poff1 + kn);
                if (dualP) {
                    P2a0 = *(const short8*)(Pb + poff0 + kn);
                    P2b0 = *(const short8*)(Pb + poff1 + kn);
                }
            } else {
                A1   = *(const short8*)(sa_src + kn);
                P1a1 = *(const short8*)(Pa + poff0 + kn);
                P1b1 = *(const short8*)(Pa + poff1 + kn);
                if (dualP) {
                    P2a1 = *(const short8*)(Pb + poff0 + kn);
                    P2b1 = *(const short8*)(Pb + poff1 + kn);
                }
            }
        }
        __syncthreads();
#pragma unroll
        for (int kh = 0; kh < 2; ++kh) {
            int ko = kh * 32 + quad * 8;
            short8 av = *(const short8*)&u.a.sA[cur][lap][m16][ko];
            short8 p1 = *(const short8*)&u.a.sP1[cur][w * 16 + m16][ko];
            acc = __builtin_amdgcn_mfma_f32_16x16x32_bf16(p1, av, acc, 0, 0, 0);
            if (dualP) {
                short8 p2 = *(const short8*)&u.a.sP2[cur][w * 16 + m16][ko];
                acc = __builtin_amdgcn_mfma_f32_16x16x32_bf16(p2, av, acc, 0, 0, 0);
            }
        }
    }
    // epilogue -> sRed, capture d into sD
    float d = rsqrtf(dspre + 1.0f + 1e-5f);
    if (cg == 0 && quad == 0) sD[lap][m16] = d;
#pragma unroll
    for (int r = 0; r < 4; ++r) {
        int c32 = cbase + r;
        float pv = bf2f(pvA[r]);
        if (dualP) pv += bf2f(pvB[r]);
        if (scaleP) pv *= d;
        sRed[lap][c32][m16] = d * (acc[r] + pv);
    }
    __syncthreads();
    // combine laps + bias + mask + relu -> sH16
#pragma unroll
    for (int s = 0; s < 2; ++s) {
        int idx = t + s * 256;
        int c32 = idx & 31, i = idx >> 5;
        float mv = mask[b * NN + i0 + i];
        float v = (sRed[0][c32][i] + sRed[1][c32][i] + gb[ch * 32 + c32]) * mv;
        sH16[i][c32] = fmaxf(v, 0.f);
    }
    __syncthreads();

    if (mode == 0) {
        // ---- phase B: partial pre for next layer via MFMA, K=32
#pragma unroll
        for (int kk = 0; kk < 8; ++kk) {
            int chunk = t + kk * 256;            // 0..2047
            int c = chunk & 127;
            int k = (chunk >> 7) * 2;            // even k
            unsigned pk = (unsigned)f2bf(gwPre[kk * 2])
                        | ((unsigned)f2bf(gwPre[kk * 2 + 1]) << 16);
            *(unsigned*)&u.b.sWT[c][k] = pk;
        }
        __syncthreads();
        float4 h0 = *(const float4*)&sH16[m16][quad * 8];
        float4 h1 = *(const float4*)&sH16[m16][quad * 8 + 4];
        short8 bfv;
        bfv[0] = f2bf(h0.x); bfv[1] = f2bf(h0.y); bfv[2] = f2bf(h0.z); bfv[3] = f2bf(h0.w);
        bfv[4] = f2bf(h1.x); bfv[5] = f2bf(h1.y); bfv[6] = f2bf(h1.z); bfv[7] = f2bf(h1.w);
        ushort_t* Q = ch ? Qb : Qa;
#pragma unroll
        for (int s2 = 0; s2 < 2; ++s2) {
            int ctile = w * 2 + s2;              // 0..7
            short8 af = *(const short8*)&u.b.sWT[ctile * 16 + m16][quad * 8];
            float4v dacc = {0.f, 0.f, 0.f, 0.f};
            dacc = __builtin_amdgcn_mfma_f32_16x16x32_bf16(af, bfv, dacc, 0, 0, 0);
            float dsc = sD[(ctile >= 4) ? 1 : 0][m16];
#pragma unroll
            for (int r = 0; r < 4; ++r) {
                int c = ctile * 16 + quad * 4 + r;
                Q[((size_t)(b * 128 + c)) * NN + i0 + m16] = f2bf(dsc * dacc[r]);
            }
        }
    } else {
        // ---- phase C: max-pool + FC
        if (t < 32) {
            float mx = 0.f;
#pragma unroll
            for (int r = 0; r < 16; ++r) mx = fmaxf(mx, sH16[r][t]);
            atomicMax(&gmax[b * 64 + ch * 32 + t], __float_as_uint(mx));
        }
        __syncthreads();
        if (t == 0) {
            __threadfence();
            int old = atomicAdd(&done[b], 1);
            lastFlag = (old == 63);
        }
        __syncthreads();
        if (lastFlag) {
            if (t < 64) {
                unsigned ub = __hip_atomic_load(&gmax[b * 64 + t],
                                                __ATOMIC_RELAXED,
                                                __HIP_MEMORY_SCOPE_AGENT);
                ((float*)sRed)[t] = __uint_as_float(ub);
            }
            __syncthreads();
            if (t < 2) {
                float a2 = fcb[t];
#pragma unroll
                for (int k = 0; k < 64; ++k)
                    a2 = fmaf(((float*)sRed)[k], fcw[k * 2 + t], a2);
                out[b * 2 + t] = a2;
            }
        }
    }
}

extern "C" void kernel_launch(void* const* d_in, const int* in_sizes, int n_in,
                              void* d_out, int out_size, void* d_ws, size_t ws_size,
                              hipStream_t stream)
{
    const float* x    = (const float*)d_in[0];
    const float* A    = (const float*)d_in[1];
    const float* mask = (const float*)d_in[2];
    const float* ew1  = (const float*)d_in[3];
    const float* eb1  = (const float*)d_in[4];
    const float* ew2  = (const float*)d_in[5];
    const float* eb2  = (const float*)d_in[6];
    const float* gw0  = (const float*)d_in[7];
    const float* gb0  = (const float*)d_in[8];
    const float* gw1  = (const float*)d_in[9];
    const float* gb1  = (const float*)d_in[10];
    const float* gw2  = (const float*)d_in[11];
    const float* gb2  = (const float*)d_in[12];
    const float* fcw  = (const float*)d_in[13];
    const float* fcb  = (const float*)d_in[14];
    float* out = (float*)d_out;
    char* ws = (char*)d_ws;

    const size_t NEL = (size_t)NB * NN * NN;      // 2,097,152
    const size_t PSL = (size_t)NB * 128 * NN;     // 524,288 (one P slice)
    float*    xab  = (float*)ws;                   ws += 262144 * 4;
    ushort_t* APh  = (ushort_t*)ws;                ws += NEL * 2;
    ushort_t* Ahs  = (ushort_t*)ws;                ws += NEL * 2;
    float*    dsum = (float*)ws;                   ws += 8192 * 4;
    ushort_t* PT_A = (ushort_t*)ws;                ws += PSL * 2;  // UNSCALED T0
    ushort_t* PB1a = (ushort_t*)ws;                ws += PSL * 2;
    ushort_t* PB1b = (ushort_t*)ws;                ws += PSL * 2;
    ushort_t* PB2a = (ushort_t*)ws;                ws += PSL * 2;
    ushort_t* PB2b = (ushort_t*)ws;                ws += PSL * 2;
    unsigned* gmax = (unsigned*)ws;                ws += 512 * 4;
    int*      done = (int*)ws;                     ws += 64 * 4;

    // K1: only the xab GEMM (gates edge tiles)
    xaxb_gemm<<<256, 256, 0, stream>>>(x, ew1, eb1, xab, dsum, gmax, done);
    // K2: edge tiles + T0 GEMM + A-conversion overlapped (1408 blocks)
    edge_plus<<<1408, 256, 0, stream>>>(x, gw0, A, Ahs, xab, ew2, eb2, mask,
                                        PT_A, APh, dsum);

    // layer 0: single-P (unscaled T0, scaleP=1), emits PB1 slices
    fused_layer<<<dim3(32, 2, NB), 256, 0, stream>>>(
        Ahs, APh, PT_A, PT_A, PB1a, PB1b, dsum, gb0, mask, gw1,
        gmax, done, fcw, fcb, out, 0, 0, 1);
    // layer 1: dual-P (PB1), emits PB2 slices
    fused_layer<<<dim3(32, 2, NB), 256, 0, stream>>>(
        Ahs, APh, PB1a, PB1b, PB2a, PB2b, dsum, gb1, mask, gw2,
        gmax, done, fcw, fcb, out, 1, 0, 0);
    // layer 2: dual-P (PB2), final max-pool + FC
    fused_layer<<<dim3(32, 2, NB), 256, 0, stream>>>(
        Ahs, APh, PB2a, PB2b, PB2a, PB2b, dsum, gb2, mask, gw2,
        gmax, done, fcw, fcb, out, 1, 1, 0);
}